// Round 9
// baseline (289.914 us; speedup 1.0000x reference)
//
#include <hip/hip_runtime.h>
#include <math.h>
#include <stdint.h>

#define LN_EPS 1e-5f
#define GRP_SHIFT 7           // 128 nodes per bucket
#define MAXBUK 1024           // N <= 131072
#define PCHUNK 4096           // edges per partition block (1024 threads x 4)

// ---------- bf16 helpers (RNE) ----------
__device__ __forceinline__ unsigned short f2bf(float f) {
  unsigned int u = __float_as_uint(f);
  unsigned int r = u + 0x7fffu + ((u >> 16) & 1u);
  return (unsigned short)(r >> 16);
}
__device__ __forceinline__ float bfLo(unsigned v) { return __uint_as_float(v << 16); }
__device__ __forceinline__ float bfHi(unsigned v) { return __uint_as_float(v & 0xffff0000u); }

// ---------- CSR build, bucketed counting sort ----------
__global__ __launch_bounds__(1024) void k_bucket_count(const int* __restrict__ dst,
                                                       int* __restrict__ bcnt, int E, int NB) {
  __shared__ int hist[MAXBUK];
  int t = threadIdx.x;
  for (int i = t; i < NB; i += 1024) hist[i] = 0;
  __syncthreads();
  int e0 = blockIdx.x * PCHUNK;
  int e1 = min(e0 + PCHUNK, E);
#pragma unroll
  for (int j = 0; j < 4; ++j) {
    int i = e0 + t + j * 1024;
    if (i < e1) atomicAdd(&hist[dst[i] >> GRP_SHIFT], 1);
  }
  __syncthreads();
  for (int i = t; i < NB; i += 1024)
    if (hist[i]) atomicAdd(&bcnt[i], hist[i]);
}

__global__ __launch_bounds__(256) void k_bucket_scan(const int* __restrict__ cnt,
                                                     int* __restrict__ base,
                                                     int* __restrict__ cur, int NB) {
  __shared__ int ts[256];
  int t = threadIdx.x;
  int v[4];
  int s = 0;
#pragma unroll
  for (int j = 0; j < 4; ++j) { int i = t * 4 + j; v[j] = (i < NB) ? cnt[i] : 0; s += v[j]; }
  ts[t] = s;
  __syncthreads();
  for (int o = 1; o < 256; o <<= 1) {
    int x = (t >= o) ? ts[t - o] : 0;
    __syncthreads();
    ts[t] += x;
    __syncthreads();
  }
  int run = ts[t] - s;
#pragma unroll
  for (int j = 0; j < 4; ++j) {
    int i = t * 4 + j;
    if (i < NB) { base[i] = run; cur[i] = run; }
    run += v[j];
  }
  if (t == 255) base[NB] = run;  // == E
}

// partition edges into per-bucket regions; payload packed (src<<7)|dst_local (N < 2^25).
__global__ __launch_bounds__(1024) void k_partition(const int* __restrict__ src,
                                                    const int* __restrict__ dst,
                                                    int* __restrict__ bcur,
                                                    unsigned* __restrict__ pairs, int E, int NB) {
  __shared__ int hist[MAXBUK];
  __shared__ int base[MAXBUK];
  int t = threadIdx.x;
  for (int i = t; i < NB; i += 1024) hist[i] = 0;
  __syncthreads();
  int e0 = blockIdx.x * PCHUNK;
  int e1 = min(e0 + PCHUNK, E);
  int sv[4], dv[4], rk[4];
#pragma unroll
  for (int j = 0; j < 4; ++j) {
    int i = e0 + t + j * 1024;
    if (i < e1) {
      sv[j] = src[i];
      dv[j] = dst[i];
      rk[j] = atomicAdd(&hist[dv[j] >> GRP_SHIFT], 1);
    } else {
      dv[j] = -1;
    }
  }
  __syncthreads();
  for (int i = t; i < NB; i += 1024) {
    int c = hist[i];
    base[i] = c ? atomicAdd(&bcur[i], c) : 0;
  }
  __syncthreads();
#pragma unroll
  for (int j = 0; j < 4; ++j) {
    if (dv[j] >= 0) {
      int b = dv[j] >> GRP_SHIFT;
      pairs[base[b] + rk[j]] = ((unsigned)sv[j] << GRP_SHIFT) | (unsigned)(dv[j] & 127);
    }
  }
}

// per-bucket: degrees (LDS), 16-aligned per-node slots funded by a global atomic
// cursor; csr holds BYTE offsets (src*128), pad slots hold ZOFF (zero row).
__global__ __launch_bounds__(256) void k_bucket_place(const unsigned* __restrict__ pairs,
                                                      const int* __restrict__ bbase,
                                                      int* __restrict__ gcur,
                                                      int2* __restrict__ noff,
                                                      float* __restrict__ dinv,
                                                      int* __restrict__ csr, int N, int ZOFF) {
  __shared__ int cnt[128];
  __shared__ int sc[128];
  __shared__ int sbase;
  int t = threadIdx.x;
  int b = blockIdx.x;
  int node0 = b << GRP_SHIFT;
  if (t < 128) cnt[t] = 0;
  int beg = bbase[b], end = bbase[b + 1];
  __syncthreads();
  for (int i = beg + t; i < end; i += 256) atomicAdd(&cnt[pairs[i] & 127u], 1);
  __syncthreads();
  int pcnt = 0;
  if (t < 128) { pcnt = (cnt[t] + 15) & ~15; sc[t] = pcnt; }
  __syncthreads();
  for (int o = 1; o < 128; o <<= 1) {
    int x = (t < 128 && t >= o) ? sc[t - o] : 0;
    __syncthreads();
    if (t < 128) sc[t] += x;
    __syncthreads();
  }
  if (t == 127) sbase = atomicAdd(gcur, sc[127]);
  __syncthreads();
  if (t < 128) {
    int off = sbase + sc[t] - pcnt;
    int node = node0 + t;
    if (node < N) {
      int d = cnt[t];
      noff[node] = make_int2(off, off + d);
      dinv[node] = d > 0 ? rsqrtf((float)d) : 0.f;
      for (int i = off + d; i < off + pcnt; ++i) csr[i] = ZOFF;  // zero-row pads
    }
    sc[t] = off;  // becomes write cursor
  }
  __syncthreads();
  for (int i = beg + t; i < end; i += 256) {
    unsigned pk = pairs[i];
    int pos = atomicAdd(&sc[pk & 127u], 1);
    csr[pos] = (int)(pk & ~127u);  // src*128 byte offset
  }
}

// ---------- GEMM: out[m] = bf16( dinv[m] * (A[m] @ W) ), A:[M][K], W:[K][64] ----------
template <int K>
__global__ __launch_bounds__(256) void gemm_scale(const float* __restrict__ A,
                                                  const float* __restrict__ W,
                                                  const float* __restrict__ dinv,
                                                  unsigned short* __restrict__ out, int M) {
  __shared__ float xs[16][64];   // transposed A tile: xs[k][m]
  __shared__ float wsh[16][64];  // W tile: wsh[k][c]
  int t = threadIdx.x;
  int m0 = blockIdx.x * 64;
  int lm = t >> 2;
  int lk = (t & 3) << 2;
  int mr = (t & 15) << 2;
  int cc = (t >> 4) << 2;
  float acc[4][4] = {{0.f}};
  int gm = m0 + lm;
  const bool mok = gm < M;
  for (int kc = 0; kc < K; kc += 16) {
    float4 av = make_float4(0.f, 0.f, 0.f, 0.f);
    if (mok) av = *(const float4*)&A[(size_t)gm * K + kc + lk];
    float wv[4];
#pragma unroll
    for (int r = 0; r < 4; ++r) {
      int k = (t >> 6) + (r << 2);
      wv[r] = W[(size_t)(kc + k) * 64 + (t & 63)];
    }
    __syncthreads();
    xs[lk + 0][lm] = av.x;
    xs[lk + 1][lm] = av.y;
    xs[lk + 2][lm] = av.z;
    xs[lk + 3][lm] = av.w;
#pragma unroll
    for (int r = 0; r < 4; ++r) {
      int k = (t >> 6) + (r << 2);
      wsh[k][t & 63] = wv[r];
    }
    __syncthreads();
#pragma unroll
    for (int k = 0; k < 16; ++k) {
      float4 a4 = *(const float4*)&xs[k][mr];
      float4 b4 = *(const float4*)&wsh[k][cc];
      float a[4] = {a4.x, a4.y, a4.z, a4.w};
      float b[4] = {b4.x, b4.y, b4.z, b4.w};
#pragma unroll
      for (int i = 0; i < 4; ++i)
#pragma unroll
        for (int j = 0; j < 4; ++j) acc[i][j] = fmaf(a[i], b[j], acc[i][j]);
    }
  }
#pragma unroll
  for (int i = 0; i < 4; ++i) {
    int row = m0 + mr + i;
    if (row < M) {
      float sc = dinv[row];
      ushort4 o;
      o.x = f2bf(acc[i][0] * sc);
      o.y = f2bf(acc[i][1] * sc);
      o.z = f2bf(acc[i][2] * sc);
      o.w = f2bf(acc[i][3] * sc);
      *(ushort4*)&out[(size_t)row * 64 + cc] = o;
    }
  }
}

// ---------- aggregation + bias + LayerNorm + ReLU ----------
// wave per node. lane = (q = lane>>4, fl = lane&15); fl owns features 4fl..4fl+3.
// csr holds byte offsets in 16-aligned slots, zero-row padded -> branch-free,
// mask-free, shuffle-free inner loop: 1 uint4 idx load + 4 gathers per 16 edges.
__global__ __launch_bounds__(256) void k_agg(const char* __restrict__ hsb,
                                             const uint4* __restrict__ csr4,
                                             const int2* __restrict__ noff,
                                             const float* __restrict__ dinv,
                                             const float* __restrict__ b,
                                             const float* __restrict__ g,
                                             const float* __restrict__ tt,
                                             float* __restrict__ out, int n) {
  int lane = threadIdx.x & 63;
  int q = lane >> 4;
  int fl = lane & 15;
  int node = blockIdx.x * 4 + (threadIdx.x >> 6);
  if (node >= n) return;
  int2 be = noff[node];
  int ng = (be.y - be.x + 15) >> 4;   // 16-edge groups (padded slot)
  float a0 = 0.f, a1 = 0.f, a2 = 0.f, a3 = 0.f;
  unsigned fo = (unsigned)fl * 8u;
  int c4 = (be.x >> 2) + q;
  for (; ng > 0; --ng, c4 += 4) {
    uint4 iv = csr4[c4];                 // this lane's 4 edges (byte offsets)
    uint2 w0 = *(const uint2*)(hsb + (iv.x + fo));
    uint2 w1 = *(const uint2*)(hsb + (iv.y + fo));
    uint2 w2 = *(const uint2*)(hsb + (iv.z + fo));
    uint2 w3 = *(const uint2*)(hsb + (iv.w + fo));
    a0 += bfLo(w0.x); a1 += bfHi(w0.x); a2 += bfLo(w0.y); a3 += bfHi(w0.y);
    a0 += bfLo(w1.x); a1 += bfHi(w1.x); a2 += bfLo(w1.y); a3 += bfHi(w1.y);
    a0 += bfLo(w2.x); a1 += bfHi(w2.x); a2 += bfLo(w2.y); a3 += bfHi(w2.y);
    a0 += bfLo(w3.x); a1 += bfHi(w3.x); a2 += bfLo(w3.y); a3 += bfHi(w3.y);
  }

  // combine the 4 quarters (independent 2-step chains)
  a0 += __shfl_xor(a0, 16, 64); a0 += __shfl_xor(a0, 32, 64);
  a1 += __shfl_xor(a1, 16, 64); a1 += __shfl_xor(a1, 32, 64);
  a2 += __shfl_xor(a2, 16, 64); a2 += __shfl_xor(a2, 32, 64);
  a3 += __shfl_xor(a3, 16, 64); a3 += __shfl_xor(a3, 32, 64);

  float dv = dinv[node];
  float4 bb = *(const float4*)&b[fl * 4];
  float v0 = fmaf(a0, dv, bb.x);
  float v1 = fmaf(a1, dv, bb.y);
  float v2 = fmaf(a2, dv, bb.z);
  float v3 = fmaf(a3, dv, bb.w);
  float s  = v0 + v1 + v2 + v3;
  float s2 = fmaf(v0, v0, fmaf(v1, v1, fmaf(v2, v2, v3 * v3)));
#pragma unroll
  for (int m = 1; m < 16; m <<= 1) {   // two independent 4-step chains
    s  += __shfl_xor(s, m, 64);
    s2 += __shfl_xor(s2, m, 64);
  }
  float mu = s * 0.015625f;            // /64
  float var = fmaxf(s2 * 0.015625f - mu * mu, 0.f);
  float rs = rsqrtf(var + LN_EPS);
  float4 gg = *(const float4*)&g[fl * 4];
  float4 t4 = *(const float4*)&tt[fl * 4];
  if (q == 0) {
    float4 o;
    o.x = fmaxf(fmaf(gg.x * (v0 - mu), rs, t4.x), 0.f);
    o.y = fmaxf(fmaf(gg.y * (v1 - mu), rs, t4.y), 0.f);
    o.z = fmaxf(fmaf(gg.z * (v2 - mu), rs, t4.z), 0.f);
    o.w = fmaxf(fmaf(gg.w * (v3 - mu), rs, t4.w), 0.f);
    *(float4*)&out[(size_t)node * 64 + fl * 4] = o;
  }
}

// ---------- final: logits = h @ Wf + bf ; log_softmax (thread per node, 2 nodes/thread) ----------
__global__ __launch_bounds__(256) void k_final(const float* __restrict__ h,
                                               const float* __restrict__ Wf,
                                               const float* __restrict__ bf,
                                               float* __restrict__ out, int n) {
  __shared__ float Wl[64 * 40];
  __shared__ float bl[40];
  int t = threadIdx.x;
  for (int i = t; i < 64 * 40; i += 256) Wl[i] = Wf[i];
  if (t < 40) bl[t] = bf[t];
  __syncthreads();
  int n0 = blockIdx.x * 512 + t;
  int n1 = n0 + 256;
  const bool ok0 = n0 < n, ok1 = n1 < n;
  float acc0[40], acc1[40];
#pragma unroll
  for (int c = 0; c < 40; ++c) { acc0[c] = bl[c]; acc1[c] = bl[c]; }
  const float* h0 = &h[(size_t)n0 * 64];
  const float* h1 = &h[(size_t)n1 * 64];
#pragma unroll 2
  for (int k4 = 0; k4 < 16; ++k4) {
    float4 a4 = ok0 ? *(const float4*)&h0[k4 * 4] : make_float4(0.f, 0.f, 0.f, 0.f);
    float4 c4v = ok1 ? *(const float4*)&h1[k4 * 4] : make_float4(0.f, 0.f, 0.f, 0.f);
    float av[4] = {a4.x, a4.y, a4.z, a4.w};
    float bv[4] = {c4v.x, c4v.y, c4v.z, c4v.w};
#pragma unroll
    for (int j = 0; j < 4; ++j) {
      int k = k4 * 4 + j;
#pragma unroll
      for (int c4 = 0; c4 < 10; ++c4) {
        float4 w = *(const float4*)&Wl[k * 40 + c4 * 4];  // uniform -> broadcast
        acc0[c4 * 4 + 0] = fmaf(av[j], w.x, acc0[c4 * 4 + 0]);
        acc0[c4 * 4 + 1] = fmaf(av[j], w.y, acc0[c4 * 4 + 1]);
        acc0[c4 * 4 + 2] = fmaf(av[j], w.z, acc0[c4 * 4 + 2]);
        acc0[c4 * 4 + 3] = fmaf(av[j], w.w, acc0[c4 * 4 + 3]);
        acc1[c4 * 4 + 0] = fmaf(bv[j], w.x, acc1[c4 * 4 + 0]);
        acc1[c4 * 4 + 1] = fmaf(bv[j], w.y, acc1[c4 * 4 + 1]);
        acc1[c4 * 4 + 2] = fmaf(bv[j], w.z, acc1[c4 * 4 + 2]);
        acc1[c4 * 4 + 3] = fmaf(bv[j], w.w, acc1[c4 * 4 + 3]);
      }
    }
  }
  float m0 = acc0[0], m1 = acc1[0];
#pragma unroll
  for (int c = 1; c < 40; ++c) { m0 = fmaxf(m0, acc0[c]); m1 = fmaxf(m1, acc1[c]); }
  float s0 = 0.f, s1 = 0.f;
#pragma unroll
  for (int c = 0; c < 40; ++c) { s0 += expf(acc0[c] - m0); s1 += expf(acc1[c] - m1); }
  float l0 = m0 + logf(s0);
  float l1 = m1 + logf(s1);
#pragma unroll
  for (int c4 = 0; c4 < 10; ++c4) {
    if (ok0) {
      float4 o = make_float4(acc0[c4 * 4 + 0] - l0, acc0[c4 * 4 + 1] - l0,
                             acc0[c4 * 4 + 2] - l0, acc0[c4 * 4 + 3] - l0);
      *(float4*)&out[(size_t)n0 * 40 + c4 * 4] = o;
    }
    if (ok1) {
      float4 o = make_float4(acc1[c4 * 4 + 0] - l1, acc1[c4 * 4 + 1] - l1,
                             acc1[c4 * 4 + 2] - l1, acc1[c4 * 4 + 3] - l1);
      *(float4*)&out[(size_t)n1 * 40 + c4 * 4] = o;
    }
  }
}

// ---------- launch ----------
extern "C" void kernel_launch(void* const* d_in, const int* in_sizes, int n_in,
                              void* d_out, int out_size, void* d_ws, size_t ws_size,
                              hipStream_t stream) {
  const float* x  = (const float*)d_in[0];
  const int*   ei = (const int*)d_in[1];
  const float* W1 = (const float*)d_in[2];
  const float* b1 = (const float*)d_in[3];
  const float* g1 = (const float*)d_in[4];
  const float* t1 = (const float*)d_in[5];
  const float* W2 = (const float*)d_in[6];
  const float* b2 = (const float*)d_in[7];
  const float* g2 = (const float*)d_in[8];
  const float* t2 = (const float*)d_in[9];
  const float* W3 = (const float*)d_in[10];
  const float* b3 = (const float*)d_in[11];
  const float* g3 = (const float*)d_in[12];
  const float* t3 = (const float*)d_in[13];
  const float* Wf = (const float*)d_in[14];
  const float* bf = (const float*)d_in[15];
  float* out = (float*)d_out;

  const int N = in_sizes[0] / 128;
  const int E = in_sizes[1] / 2;
  const int* src = ei;
  const int* dst = ei + E;
  const int NBUK = (N + 127) >> GRP_SHIFT;
  const int NEB  = (E + PCHUNK - 1) / PCHUNK;
  const int ZOFF = N * 128;  // byte offset of the zero row in hs

  char* p = (char*)d_ws;
  auto carve = [&](size_t bytes) -> char* {
    char* r = p;
    p += (bytes + 255) & ~(size_t)255;
    return r;
  };
  int*      bcnt    = (int*)carve((size_t)(NBUK + 1) * 4);  // +1 = gcur
  int*      gcur    = bcnt + NBUK;
  int*      bbase   = (int*)carve((size_t)(NBUK + 1) * 4);
  int*      bcur    = (int*)carve((size_t)NBUK * 4);
  unsigned* pairs   = (unsigned*)carve((size_t)E * 4);
  int*      csr     = (int*)carve(((size_t)E + 15 * (size_t)N + 256) * 4);
  int2*     noff    = (int2*)carve((size_t)N * 8);
  float*    dinv    = (float*)carve((size_t)N * 4);
  unsigned short* hs = (unsigned short*)carve(((size_t)N * 64 + 64) * 2);  // +1 zero row
  float*    hA      = (float*)carve((size_t)N * 64 * 4);
  float*    hB      = (float*)carve((size_t)N * 64 * 4);
  (void)ws_size; (void)n_in; (void)out_size;

  dim3 B(256);
  dim3 B1K(1024);
  hipMemsetAsync(bcnt, 0, (size_t)(NBUK + 1) * 4, stream);   // bcnt + gcur
  hipMemsetAsync(hs + (size_t)N * 64, 0, 128, stream);       // zero row
  k_bucket_count<<<dim3(NEB), B1K, 0, stream>>>(dst, bcnt, E, NBUK);
  k_bucket_scan<<<dim3(1), B, 0, stream>>>(bcnt, bbase, bcur, NBUK);
  k_partition<<<dim3(NEB), B1K, 0, stream>>>(src, dst, bcur, pairs, E, NBUK);
  k_bucket_place<<<dim3(NBUK), B, 0, stream>>>(pairs, bbase, gcur, noff, dinv, csr, N, ZOFF);

  const int GB = (N + 63) / 64;
  const int GA = (N + 3) / 4;
  const int GF = (N + 511) / 512;
  // layer 1
  gemm_scale<128><<<dim3(GB), B, 0, stream>>>(x, W1, dinv, hs, N);
  k_agg<<<dim3(GA), B, 0, stream>>>((const char*)hs, (const uint4*)csr, noff, dinv, b1, g1, t1, hA, N);
  // layer 2
  gemm_scale<64><<<dim3(GB), B, 0, stream>>>(hA, W2, dinv, hs, N);
  k_agg<<<dim3(GA), B, 0, stream>>>((const char*)hs, (const uint4*)csr, noff, dinv, b2, g2, t2, hB, N);
  // layer 3
  gemm_scale<64><<<dim3(GB), B, 0, stream>>>(hB, W3, dinv, hs, N);
  k_agg<<<dim3(GA), B, 0, stream>>>((const char*)hs, (const uint4*)csr, noff, dinv, b3, g3, t3, hA, N);
  // final projection + log_softmax
  k_final<<<dim3(GF), B, 0, stream>>>(hA, Wf, bf, out, N);
}

// Round 12
// 277.444 us; speedup vs baseline: 1.0449x; 1.0449x over previous
//
#include <hip/hip_runtime.h>
#include <math.h>
#include <stdint.h>

#define LN_EPS 1e-5f
#define GRP_SHIFT 7           // 128 nodes per bucket
#define MAXBUK 1024           // N <= 131072
#define PCHUNK 4096           // edges per partition block (1024 threads x 4)
#define BCAP 4096             // fixed per-bucket capacity (mean 2048, huge margin)

// ---------- bf16 helpers (RNE) ----------
__device__ __forceinline__ unsigned short f2bf(float f) {
  unsigned int u = __float_as_uint(f);
  unsigned int r = u + 0x7fffu + ((u >> 16) & 1u);
  return (unsigned short)(r >> 16);
}
__device__ __forceinline__ float bfLo(unsigned v) { return __uint_as_float(v << 16); }
__device__ __forceinline__ float bfHi(unsigned v) { return __uint_as_float(v & 0xffff0000u); }

// ---------- CSR build: single-pass partition into fixed-capacity buckets ----------
// payload packed (src<<7)|dst_local (N < 2^25); per-(block,bucket) rank from LDS hist.
__global__ __launch_bounds__(1024) void k_partition(const int* __restrict__ src,
                                                    const int* __restrict__ dst,
                                                    int* __restrict__ bcnt,
                                                    unsigned* __restrict__ pairs, int E, int NB) {
  __shared__ int hist[MAXBUK];
  __shared__ int base[MAXBUK];
  int t = threadIdx.x;
  for (int i = t; i < NB; i += 1024) hist[i] = 0;
  __syncthreads();
  int e0 = blockIdx.x * PCHUNK;
  int e1 = min(e0 + PCHUNK, E);
  int sv[4], dv[4], rk[4];
#pragma unroll
  for (int j = 0; j < 4; ++j) {
    int i = e0 + t + j * 1024;
    if (i < e1) {
      sv[j] = src[i];
      dv[j] = dst[i];
      rk[j] = atomicAdd(&hist[dv[j] >> GRP_SHIFT], 1);
    } else {
      dv[j] = -1;
    }
  }
  __syncthreads();
  for (int i = t; i < NB; i += 1024) {
    int c = hist[i];
    base[i] = c ? (i * BCAP + atomicAdd(&bcnt[i], c)) : 0;
  }
  __syncthreads();
#pragma unroll
  for (int j = 0; j < 4; ++j) {
    if (dv[j] >= 0) {
      int b = dv[j] >> GRP_SHIFT;
      pairs[base[b] + rk[j]] = ((unsigned)sv[j] << GRP_SHIFT) | (unsigned)(dv[j] & 127);
    }
  }
}

// per-bucket: degrees (LDS), 16-aligned per-node slots funded by a global atomic
// cursor; csr holds BYTE offsets (src*128), pad slots hold ZOFF (zero row).
__global__ __launch_bounds__(256) void k_bucket_place(const unsigned* __restrict__ pairs,
                                                      const int* __restrict__ bcnt,
                                                      int* __restrict__ gcur,
                                                      int2* __restrict__ noff,
                                                      float* __restrict__ dinv,
                                                      int* __restrict__ csr, int N, int ZOFF) {
  __shared__ int cnt[128];
  __shared__ int sc[128];
  __shared__ int sbase;
  int t = threadIdx.x;
  int b = blockIdx.x;
  int node0 = b << GRP_SHIFT;
  if (t < 128) cnt[t] = 0;
  int beg = b * BCAP;
  int end = beg + bcnt[b];
  __syncthreads();
  for (int i = beg + t; i < end; i += 256) atomicAdd(&cnt[pairs[i] & 127u], 1);
  __syncthreads();
  int pcnt = 0;
  if (t < 128) { pcnt = (cnt[t] + 15) & ~15; sc[t] = pcnt; }
  __syncthreads();
  for (int o = 1; o < 128; o <<= 1) {
    int x = (t < 128 && t >= o) ? sc[t - o] : 0;
    __syncthreads();
    if (t < 128) sc[t] += x;
    __syncthreads();
  }
  if (t == 127) sbase = atomicAdd(gcur, sc[127]);
  __syncthreads();
  if (t < 128) {
    int off = sbase + sc[t] - pcnt;
    int node = node0 + t;
    if (node < N) {
      int d = cnt[t];
      noff[node] = make_int2(off, off + d);
      dinv[node] = d > 0 ? rsqrtf((float)d) : 0.f;
      for (int i = off + d; i < off + pcnt; ++i) csr[i] = ZOFF;  // zero-row pads
    }
    sc[t] = off;  // becomes write cursor
  }
  __syncthreads();
  for (int i = beg + t; i < end; i += 256) {
    unsigned pk = pairs[i];
    int pos = atomicAdd(&sc[pk & 127u], 1);
    csr[pos] = (int)(pk & ~127u);  // src*128 byte offset
  }
}

// ---------- GEMM: out[m] = bf16( dinv[m] * (A[m] @ W) ), A:[M][K] f32, W:[K][64] ----------
template <int K>
__global__ __launch_bounds__(256) void gemm_scale(const float* __restrict__ A,
                                                  const float* __restrict__ W,
                                                  const float* __restrict__ dinv,
                                                  unsigned short* __restrict__ out, int M) {
  __shared__ float xs[16][64];   // transposed A tile: xs[k][m]
  __shared__ float wsh[16][64];  // W tile: wsh[k][c]
  int t = threadIdx.x;
  int m0 = blockIdx.x * 64;
  int lm = t >> 2;
  int lk = (t & 3) << 2;
  int mr = (t & 15) << 2;
  int cc = (t >> 4) << 2;
  float acc[4][4] = {{0.f}};
  int gm = m0 + lm;
  const bool mok = gm < M;
  for (int kc = 0; kc < K; kc += 16) {
    float4 av = make_float4(0.f, 0.f, 0.f, 0.f);
    if (mok) av = *(const float4*)&A[(size_t)gm * K + kc + lk];
    float wv[4];
#pragma unroll
    for (int r = 0; r < 4; ++r) {
      int k = (t >> 6) + (r << 2);
      wv[r] = W[(size_t)(kc + k) * 64 + (t & 63)];
    }
    __syncthreads();
    xs[lk + 0][lm] = av.x;
    xs[lk + 1][lm] = av.y;
    xs[lk + 2][lm] = av.z;
    xs[lk + 3][lm] = av.w;
#pragma unroll
    for (int r = 0; r < 4; ++r) {
      int k = (t >> 6) + (r << 2);
      wsh[k][t & 63] = wv[r];
    }
    __syncthreads();
#pragma unroll
    for (int k = 0; k < 16; ++k) {
      float4 a4 = *(const float4*)&xs[k][mr];
      float4 b4 = *(const float4*)&wsh[k][cc];
      float a[4] = {a4.x, a4.y, a4.z, a4.w};
      float b[4] = {b4.x, b4.y, b4.z, b4.w};
#pragma unroll
      for (int i = 0; i < 4; ++i)
#pragma unroll
        for (int j = 0; j < 4; ++j) acc[i][j] = fmaf(a[i], b[j], acc[i][j]);
    }
  }
#pragma unroll
  for (int i = 0; i < 4; ++i) {
    int row = m0 + mr + i;
    if (row < M) {
      float sc = dinv[row];
      ushort4 o;
      o.x = f2bf(acc[i][0] * sc);
      o.y = f2bf(acc[i][1] * sc);
      o.z = f2bf(acc[i][2] * sc);
      o.w = f2bf(acc[i][3] * sc);
      *(ushort4*)&out[(size_t)row * 64 + cc] = o;
    }
  }
}

// ---------- aggregation + bias + LayerNorm + ReLU (round-9 proven) ----------
// wave per node. lane = (q = lane>>4, fl = lane&15); fl owns features 4fl..4fl+3.
// csr holds byte offsets in 16-aligned, zero-row-padded slots -> branch/mask/shuffle-free
// inner loop: 1 uint4 idx load + 4 gathers per 16 edges.
__global__ __launch_bounds__(256) void k_agg(const char* __restrict__ hsb,
                                             const uint4* __restrict__ csr4,
                                             const int2* __restrict__ noff,
                                             const float* __restrict__ dinv,
                                             const float* __restrict__ b,
                                             const float* __restrict__ g,
                                             const float* __restrict__ tt,
                                             float* __restrict__ out, int n) {
  int lane = threadIdx.x & 63;
  int q = lane >> 4;
  int fl = lane & 15;
  int node = blockIdx.x * 4 + (threadIdx.x >> 6);
  if (node >= n) return;
  int2 be = noff[node];
  int ng = (be.y - be.x + 15) >> 4;   // 16-edge groups (padded slot)
  float a0 = 0.f, a1 = 0.f, a2 = 0.f, a3 = 0.f;
  unsigned fo = (unsigned)fl * 8u;
  int c4 = (be.x >> 2) + q;
  for (; ng > 0; --ng, c4 += 4) {
    uint4 iv = csr4[c4];                 // this lane's 4 edges (byte offsets)
    uint2 w0 = *(const uint2*)(hsb + (iv.x + fo));
    uint2 w1 = *(const uint2*)(hsb + (iv.y + fo));
    uint2 w2 = *(const uint2*)(hsb + (iv.z + fo));
    uint2 w3 = *(const uint2*)(hsb + (iv.w + fo));
    a0 += bfLo(w0.x); a1 += bfHi(w0.x); a2 += bfLo(w0.y); a3 += bfHi(w0.y);
    a0 += bfLo(w1.x); a1 += bfHi(w1.x); a2 += bfLo(w1.y); a3 += bfHi(w1.y);
    a0 += bfLo(w2.x); a1 += bfHi(w2.x); a2 += bfLo(w2.y); a3 += bfHi(w2.y);
    a0 += bfLo(w3.x); a1 += bfHi(w3.x); a2 += bfLo(w3.y); a3 += bfHi(w3.y);
  }

  // combine the 4 quarters (independent 2-step chains)
  a0 += __shfl_xor(a0, 16, 64); a0 += __shfl_xor(a0, 32, 64);
  a1 += __shfl_xor(a1, 16, 64); a1 += __shfl_xor(a1, 32, 64);
  a2 += __shfl_xor(a2, 16, 64); a2 += __shfl_xor(a2, 32, 64);
  a3 += __shfl_xor(a3, 16, 64); a3 += __shfl_xor(a3, 32, 64);

  float dv = dinv[node];
  float4 bb = *(const float4*)&b[fl * 4];
  float v0 = fmaf(a0, dv, bb.x);
  float v1 = fmaf(a1, dv, bb.y);
  float v2 = fmaf(a2, dv, bb.z);
  float v3 = fmaf(a3, dv, bb.w);
  float s  = v0 + v1 + v2 + v3;
  float s2 = fmaf(v0, v0, fmaf(v1, v1, fmaf(v2, v2, v3 * v3)));
#pragma unroll
  for (int m = 1; m < 16; m <<= 1) {   // two independent 4-step chains
    s  += __shfl_xor(s, m, 64);
    s2 += __shfl_xor(s2, m, 64);
  }
  float mu = s * 0.015625f;            // /64
  float var = fmaxf(s2 * 0.015625f - mu * mu, 0.f);
  float rs = rsqrtf(var + LN_EPS);
  float4 gg = *(const float4*)&g[fl * 4];
  float4 t4 = *(const float4*)&tt[fl * 4];
  if (q == 0) {
    float4 o;
    o.x = fmaxf(fmaf(gg.x * (v0 - mu), rs, t4.x), 0.f);
    o.y = fmaxf(fmaf(gg.y * (v1 - mu), rs, t4.y), 0.f);
    o.z = fmaxf(fmaf(gg.z * (v2 - mu), rs, t4.z), 0.f);
    o.w = fmaxf(fmaf(gg.w * (v3 - mu), rs, t4.w), 0.f);
    *(float4*)&out[(size_t)node * 64 + fl * 4] = o;
  }
}

// ---------- final: logits = h @ Wf + bf ; log_softmax (thread per node, 2 nodes/thread) ----------
__global__ __launch_bounds__(256) void k_final(const float* __restrict__ h,
                                               const float* __restrict__ Wf,
                                               const float* __restrict__ bf,
                                               float* __restrict__ out, int n) {
  __shared__ float Wl[64 * 40];
  __shared__ float bl[40];
  int t = threadIdx.x;
  for (int i = t; i < 64 * 40; i += 256) Wl[i] = Wf[i];
  if (t < 40) bl[t] = bf[t];
  __syncthreads();
  int n0 = blockIdx.x * 512 + t;
  int n1 = n0 + 256;
  const bool ok0 = n0 < n, ok1 = n1 < n;
  float acc0[40], acc1[40];
#pragma unroll
  for (int c = 0; c < 40; ++c) { acc0[c] = bl[c]; acc1[c] = bl[c]; }
  const float* h0 = &h[(size_t)n0 * 64];
  const float* h1 = &h[(size_t)n1 * 64];
#pragma unroll 2
  for (int k4 = 0; k4 < 16; ++k4) {
    float4 a4 = ok0 ? *(const float4*)&h0[k4 * 4] : make_float4(0.f, 0.f, 0.f, 0.f);
    float4 c4v = ok1 ? *(const float4*)&h1[k4 * 4] : make_float4(0.f, 0.f, 0.f, 0.f);
    float av[4] = {a4.x, a4.y, a4.z, a4.w};
    float bv[4] = {c4v.x, c4v.y, c4v.z, c4v.w};
#pragma unroll
    for (int j = 0; j < 4; ++j) {
      int k = k4 * 4 + j;
#pragma unroll
      for (int c4 = 0; c4 < 10; ++c4) {
        float4 w = *(const float4*)&Wl[k * 40 + c4 * 4];  // uniform -> broadcast
        acc0[c4 * 4 + 0] = fmaf(av[j], w.x, acc0[c4 * 4 + 0]);
        acc0[c4 * 4 + 1] = fmaf(av[j], w.y, acc0[c4 * 4 + 1]);
        acc0[c4 * 4 + 2] = fmaf(av[j], w.z, acc0[c4 * 4 + 2]);
        acc0[c4 * 4 + 3] = fmaf(av[j], w.w, acc0[c4 * 4 + 3]);
        acc1[c4 * 4 + 0] = fmaf(bv[j], w.x, acc1[c4 * 4 + 0]);
        acc1[c4 * 4 + 1] = fmaf(bv[j], w.y, acc1[c4 * 4 + 1]);
        acc1[c4 * 4 + 2] = fmaf(bv[j], w.z, acc1[c4 * 4 + 2]);
        acc1[c4 * 4 + 3] = fmaf(bv[j], w.w, acc1[c4 * 4 + 3]);
      }
    }
  }
  float m0 = acc0[0], m1 = acc1[0];
#pragma unroll
  for (int c = 1; c < 40; ++c) { m0 = fmaxf(m0, acc0[c]); m1 = fmaxf(m1, acc1[c]); }
  float s0 = 0.f, s1 = 0.f;
#pragma unroll
  for (int c = 0; c < 40; ++c) { s0 += expf(acc0[c] - m0); s1 += expf(acc1[c] - m1); }
  float l0 = m0 + logf(s0);
  float l1 = m1 + logf(s1);
#pragma unroll
  for (int c4 = 0; c4 < 10; ++c4) {
    if (ok0) {
      float4 o = make_float4(acc0[c4 * 4 + 0] - l0, acc0[c4 * 4 + 1] - l0,
                             acc0[c4 * 4 + 2] - l0, acc0[c4 * 4 + 3] - l0);
      *(float4*)&out[(size_t)n0 * 40 + c4 * 4] = o;
    }
    if (ok1) {
      float4 o = make_float4(acc1[c4 * 4 + 0] - l1, acc1[c4 * 4 + 1] - l1,
                             acc1[c4 * 4 + 2] - l1, acc1[c4 * 4 + 3] - l1);
      *(float4*)&out[(size_t)n1 * 40 + c4 * 4] = o;
    }
  }
}

// ---------- launch ----------
extern "C" void kernel_launch(void* const* d_in, const int* in_sizes, int n_in,
                              void* d_out, int out_size, void* d_ws, size_t ws_size,
                              hipStream_t stream) {
  const float* x  = (const float*)d_in[0];
  const int*   ei = (const int*)d_in[1];
  const float* W1 = (const float*)d_in[2];
  const float* b1 = (const float*)d_in[3];
  const float* g1 = (const float*)d_in[4];
  const float* t1 = (const float*)d_in[5];
  const float* W2 = (const float*)d_in[6];
  const float* b2 = (const float*)d_in[7];
  const float* g2 = (const float*)d_in[8];
  const float* t2 = (const float*)d_in[9];
  const float* W3 = (const float*)d_in[10];
  const float* b3 = (const float*)d_in[11];
  const float* g3 = (const float*)d_in[12];
  const float* t3 = (const float*)d_in[13];
  const float* Wf = (const float*)d_in[14];
  const float* bf = (const float*)d_in[15];
  float* out = (float*)d_out;

  const int N = in_sizes[0] / 128;
  const int E = in_sizes[1] / 2;
  const int* src = ei;
  const int* dst = ei + E;
  const int NBUK = (N + 127) >> GRP_SHIFT;
  const int NEB  = (E + PCHUNK - 1) / PCHUNK;
  const int ZOFF = N * 128;  // byte offset of the zero row in hs

  char* p = (char*)d_ws;
  auto carve = [&](size_t bytes) -> char* {
    char* r = p;
    p += (bytes + 255) & ~(size_t)255;
    return r;
  };
  int*      bcnt    = (int*)carve((size_t)(NBUK + 1) * 4);  // +1 = gcur
  int*      gcur    = bcnt + NBUK;
  unsigned* pairs   = (unsigned*)carve((size_t)NBUK * BCAP * 4);
  int*      csr     = (int*)carve(((size_t)E + 15 * (size_t)N + 256) * 4);
  int2*     noff    = (int2*)carve((size_t)N * 8);
  float*    dinv    = (float*)carve((size_t)N * 4);
  unsigned short* hs = (unsigned short*)carve(((size_t)N * 64 + 64) * 2);  // +1 zero row
  float*    hA      = (float*)carve((size_t)N * 64 * 4);
  float*    hB      = (float*)carve((size_t)N * 64 * 4);
  (void)ws_size; (void)n_in; (void)out_size;

  dim3 B(256);
  dim3 B1K(1024);
  (void)hipMemsetAsync(bcnt, 0, (size_t)(NBUK + 1) * 4, stream);   // bcnt + gcur
  (void)hipMemsetAsync(hs + (size_t)N * 64, 0, 128, stream);       // zero row
  k_partition<<<dim3(NEB), B1K, 0, stream>>>(src, dst, bcnt, pairs, E, NBUK);
  k_bucket_place<<<dim3(NBUK), B, 0, stream>>>(pairs, bcnt, gcur, noff, dinv, csr, N, ZOFF);

  const int GB = (N + 63) / 64;
  const int GA = (N + 3) / 4;
  const int GF = (N + 511) / 512;
  // layer 1
  gemm_scale<128><<<dim3(GB), B, 0, stream>>>(x, W1, dinv, hs, N);
  k_agg<<<dim3(GA), B, 0, stream>>>((const char*)hs, (const uint4*)csr, noff, dinv, b1, g1, t1, hA, N);
  // layer 2
  gemm_scale<64><<<dim3(GB), B, 0, stream>>>(hA, W2, dinv, hs, N);
  k_agg<<<dim3(GA), B, 0, stream>>>((const char*)hs, (const uint4*)csr, noff, dinv, b2, g2, t2, hB, N);
  // layer 3
  gemm_scale<64><<<dim3(GB), B, 0, stream>>>(hB, W3, dinv, hs, N);
  k_agg<<<dim3(GA), B, 0, stream>>>((const char*)hs, (const uint4*)csr, noff, dinv, b3, g3, t3, hA, N);
  // final projection + log_softmax
  k_final<<<dim3(GF), B, 0, stream>>>(hA, Wf, bf, out, N);
}

// Round 13
// 276.982 us; speedup vs baseline: 1.0467x; 1.0017x over previous
//
#include <hip/hip_runtime.h>
#include <math.h>
#include <stdint.h>

#define LN_EPS 1e-5f
#define GRP_SHIFT 7           // 128 nodes per bucket
#define MAXBUK 1024           // N <= 131072
#define PCHUNK 4096           // edges per partition block (1024 threads x 4)
#define BCAP 4096             // fixed per-bucket capacity (mean 2048, huge margin)

// ---------- bf16 helpers (RNE) ----------
__device__ __forceinline__ unsigned short f2bf(float f) {
  unsigned int u = __float_as_uint(f);
  unsigned int r = u + 0x7fffu + ((u >> 16) & 1u);
  return (unsigned short)(r >> 16);
}
__device__ __forceinline__ float bfLo(unsigned v) { return __uint_as_float(v << 16); }
__device__ __forceinline__ float bfHi(unsigned v) { return __uint_as_float(v & 0xffff0000u); }

// ---------- CSR build: single-pass partition into fixed-capacity buckets ----------
// payload packed (src<<7)|dst_local (N < 2^25); per-(block,bucket) rank from LDS hist.
__global__ __launch_bounds__(1024) void k_partition(const int* __restrict__ src,
                                                    const int* __restrict__ dst,
                                                    int* __restrict__ bcnt,
                                                    unsigned* __restrict__ pairs, int E, int NB) {
  __shared__ int hist[MAXBUK];
  __shared__ int base[MAXBUK];
  int t = threadIdx.x;
  for (int i = t; i < NB; i += 1024) hist[i] = 0;
  __syncthreads();
  int e0 = blockIdx.x * PCHUNK;
  int e1 = min(e0 + PCHUNK, E);
  int sv[4], dv[4], rk[4];
#pragma unroll
  for (int j = 0; j < 4; ++j) {
    int i = e0 + t + j * 1024;
    if (i < e1) {
      sv[j] = src[i];
      dv[j] = dst[i];
      rk[j] = atomicAdd(&hist[dv[j] >> GRP_SHIFT], 1);
    } else {
      dv[j] = -1;
    }
  }
  __syncthreads();
  for (int i = t; i < NB; i += 1024) {
    int c = hist[i];
    base[i] = c ? (i * BCAP + atomicAdd(&bcnt[i], c)) : 0;
  }
  __syncthreads();
#pragma unroll
  for (int j = 0; j < 4; ++j) {
    if (dv[j] >= 0) {
      int b = dv[j] >> GRP_SHIFT;
      pairs[base[b] + rk[j]] = ((unsigned)sv[j] << GRP_SHIFT) | (unsigned)(dv[j] & 127);
    }
  }
}

// per-bucket: degrees (LDS), 16-aligned per-node slots funded by a global atomic
// cursor; csr holds BYTE offsets (src*128), pad slots hold ZOFF (zero row).
__global__ __launch_bounds__(256) void k_bucket_place(const unsigned* __restrict__ pairs,
                                                      const int* __restrict__ bcnt,
                                                      int* __restrict__ gcur,
                                                      int2* __restrict__ noff,
                                                      float* __restrict__ dinv,
                                                      int* __restrict__ csr, int N, int ZOFF) {
  __shared__ int cnt[128];
  __shared__ int sc[128];
  __shared__ int sbase;
  int t = threadIdx.x;
  int b = blockIdx.x;
  int node0 = b << GRP_SHIFT;
  if (t < 128) cnt[t] = 0;
  int beg = b * BCAP;
  int end = beg + bcnt[b];
  __syncthreads();
  for (int i = beg + t; i < end; i += 256) atomicAdd(&cnt[pairs[i] & 127u], 1);
  __syncthreads();
  int pcnt = 0;
  if (t < 128) { pcnt = (cnt[t] + 15) & ~15; sc[t] = pcnt; }
  __syncthreads();
  for (int o = 1; o < 128; o <<= 1) {
    int x = (t < 128 && t >= o) ? sc[t - o] : 0;
    __syncthreads();
    if (t < 128) sc[t] += x;
    __syncthreads();
  }
  if (t == 127) sbase = atomicAdd(gcur, sc[127]);
  __syncthreads();
  if (t < 128) {
    int off = sbase + sc[t] - pcnt;
    int node = node0 + t;
    if (node < N) {
      int d = cnt[t];
      noff[node] = make_int2(off, off + d);
      dinv[node] = d > 0 ? rsqrtf((float)d) : 0.f;
      for (int i = off + d; i < off + pcnt; ++i) csr[i] = ZOFF;  // zero-row pads
    }
    sc[t] = off;  // becomes write cursor
  }
  __syncthreads();
  for (int i = beg + t; i < end; i += 256) {
    unsigned pk = pairs[i];
    int pos = atomicAdd(&sc[pk & 127u], 1);
    csr[pos] = (int)(pk & ~127u);  // src*128 byte offset
  }
}

// ---------- GEMM: out[m] = bf16( dinv[m] * (A[m] @ W) ), A:[M][K] f32, W:[K][64] ----------
template <int K>
__global__ __launch_bounds__(256) void gemm_scale(const float* __restrict__ A,
                                                  const float* __restrict__ W,
                                                  const float* __restrict__ dinv,
                                                  unsigned short* __restrict__ out, int M) {
  __shared__ float xs[16][64];   // transposed A tile: xs[k][m]
  __shared__ float wsh[16][64];  // W tile: wsh[k][c]
  int t = threadIdx.x;
  int m0 = blockIdx.x * 64;
  int lm = t >> 2;
  int lk = (t & 3) << 2;
  int mr = (t & 15) << 2;
  int cc = (t >> 4) << 2;
  float acc[4][4] = {{0.f}};
  int gm = m0 + lm;
  const bool mok = gm < M;
  for (int kc = 0; kc < K; kc += 16) {
    float4 av = make_float4(0.f, 0.f, 0.f, 0.f);
    if (mok) av = *(const float4*)&A[(size_t)gm * K + kc + lk];
    float wv[4];
#pragma unroll
    for (int r = 0; r < 4; ++r) {
      int k = (t >> 6) + (r << 2);
      wv[r] = W[(size_t)(kc + k) * 64 + (t & 63)];
    }
    __syncthreads();
    xs[lk + 0][lm] = av.x;
    xs[lk + 1][lm] = av.y;
    xs[lk + 2][lm] = av.z;
    xs[lk + 3][lm] = av.w;
#pragma unroll
    for (int r = 0; r < 4; ++r) {
      int k = (t >> 6) + (r << 2);
      wsh[k][t & 63] = wv[r];
    }
    __syncthreads();
#pragma unroll
    for (int k = 0; k < 16; ++k) {
      float4 a4 = *(const float4*)&xs[k][mr];
      float4 b4 = *(const float4*)&wsh[k][cc];
      float a[4] = {a4.x, a4.y, a4.z, a4.w};
      float b[4] = {b4.x, b4.y, b4.z, b4.w};
#pragma unroll
      for (int i = 0; i < 4; ++i)
#pragma unroll
        for (int j = 0; j < 4; ++j) acc[i][j] = fmaf(a[i], b[j], acc[i][j]);
    }
  }
#pragma unroll
  for (int i = 0; i < 4; ++i) {
    int row = m0 + mr + i;
    if (row < M) {
      float sc = dinv[row];
      ushort4 o;
      o.x = f2bf(acc[i][0] * sc);
      o.y = f2bf(acc[i][1] * sc);
      o.z = f2bf(acc[i][2] * sc);
      o.w = f2bf(acc[i][3] * sc);
      *(ushort4*)&out[(size_t)row * 64 + cc] = o;
    }
  }
}

// ---------- aggregation + bias + LayerNorm + ReLU (round-9 proven) ----------
// wave per node. lane = (q = lane>>4, fl = lane&15); fl owns features 4fl..4fl+3.
// csr holds byte offsets in 16-aligned, zero-row-padded slots -> branch/mask/shuffle-free
// inner loop: 1 uint4 idx load + 4 gathers per 16 edges.
__global__ __launch_bounds__(256) void k_agg(const char* __restrict__ hsb,
                                             const uint4* __restrict__ csr4,
                                             const int2* __restrict__ noff,
                                             const float* __restrict__ dinv,
                                             const float* __restrict__ b,
                                             const float* __restrict__ g,
                                             const float* __restrict__ tt,
                                             float* __restrict__ out, int n) {
  int lane = threadIdx.x & 63;
  int q = lane >> 4;
  int fl = lane & 15;
  int node = blockIdx.x * 4 + (threadIdx.x >> 6);
  if (node >= n) return;
  int2 be = noff[node];
  int ng = (be.y - be.x + 15) >> 4;   // 16-edge groups (padded slot)
  float a0 = 0.f, a1 = 0.f, a2 = 0.f, a3 = 0.f;
  unsigned fo = (unsigned)fl * 8u;
  int c4 = (be.x >> 2) + q;
  for (; ng > 0; --ng, c4 += 4) {
    uint4 iv = csr4[c4];                 // this lane's 4 edges (byte offsets)
    uint2 w0 = *(const uint2*)(hsb + (iv.x + fo));
    uint2 w1 = *(const uint2*)(hsb + (iv.y + fo));
    uint2 w2 = *(const uint2*)(hsb + (iv.z + fo));
    uint2 w3 = *(const uint2*)(hsb + (iv.w + fo));
    a0 += bfLo(w0.x); a1 += bfHi(w0.x); a2 += bfLo(w0.y); a3 += bfHi(w0.y);
    a0 += bfLo(w1.x); a1 += bfHi(w1.x); a2 += bfLo(w1.y); a3 += bfHi(w1.y);
    a0 += bfLo(w2.x); a1 += bfHi(w2.x); a2 += bfLo(w2.y); a3 += bfHi(w2.y);
    a0 += bfLo(w3.x); a1 += bfHi(w3.x); a2 += bfLo(w3.y); a3 += bfHi(w3.y);
  }

  // combine the 4 quarters (independent 2-step chains)
  a0 += __shfl_xor(a0, 16, 64); a0 += __shfl_xor(a0, 32, 64);
  a1 += __shfl_xor(a1, 16, 64); a1 += __shfl_xor(a1, 32, 64);
  a2 += __shfl_xor(a2, 16, 64); a2 += __shfl_xor(a2, 32, 64);
  a3 += __shfl_xor(a3, 16, 64); a3 += __shfl_xor(a3, 32, 64);

  float dv = dinv[node];
  float4 bb = *(const float4*)&b[fl * 4];
  float v0 = fmaf(a0, dv, bb.x);
  float v1 = fmaf(a1, dv, bb.y);
  float v2 = fmaf(a2, dv, bb.z);
  float v3 = fmaf(a3, dv, bb.w);
  float s  = v0 + v1 + v2 + v3;
  float s2 = fmaf(v0, v0, fmaf(v1, v1, fmaf(v2, v2, v3 * v3)));
#pragma unroll
  for (int m = 1; m < 16; m <<= 1) {   // two independent 4-step chains
    s  += __shfl_xor(s, m, 64);
    s2 += __shfl_xor(s2, m, 64);
  }
  float mu = s * 0.015625f;            // /64
  float var = fmaxf(s2 * 0.015625f - mu * mu, 0.f);
  float rs = rsqrtf(var + LN_EPS);
  float4 gg = *(const float4*)&g[fl * 4];
  float4 t4 = *(const float4*)&tt[fl * 4];
  if (q == 0) {
    float4 o;
    o.x = fmaxf(fmaf(gg.x * (v0 - mu), rs, t4.x), 0.f);
    o.y = fmaxf(fmaf(gg.y * (v1 - mu), rs, t4.y), 0.f);
    o.z = fmaxf(fmaf(gg.z * (v2 - mu), rs, t4.z), 0.f);
    o.w = fmaxf(fmaf(gg.w * (v3 - mu), rs, t4.w), 0.f);
    *(float4*)&out[(size_t)node * 64 + fl * 4] = o;
  }
}

// ---------- final: logits = h @ Wf + bf ; log_softmax (thread per node, 2 nodes/thread) ----------
__global__ __launch_bounds__(256) void k_final(const float* __restrict__ h,
                                               const float* __restrict__ Wf,
                                               const float* __restrict__ bf,
                                               float* __restrict__ out, int n) {
  __shared__ float Wl[64 * 40];
  __shared__ float bl[40];
  int t = threadIdx.x;
  for (int i = t; i < 64 * 40; i += 256) Wl[i] = Wf[i];
  if (t < 40) bl[t] = bf[t];
  __syncthreads();
  int n0 = blockIdx.x * 512 + t;
  int n1 = n0 + 256;
  const bool ok0 = n0 < n, ok1 = n1 < n;
  float acc0[40], acc1[40];
#pragma unroll
  for (int c = 0; c < 40; ++c) { acc0[c] = bl[c]; acc1[c] = bl[c]; }
  const float* h0 = &h[(size_t)n0 * 64];
  const float* h1 = &h[(size_t)n1 * 64];
#pragma unroll 2
  for (int k4 = 0; k4 < 16; ++k4) {
    float4 a4 = ok0 ? *(const float4*)&h0[k4 * 4] : make_float4(0.f, 0.f, 0.f, 0.f);
    float4 c4v = ok1 ? *(const float4*)&h1[k4 * 4] : make_float4(0.f, 0.f, 0.f, 0.f);
    float av[4] = {a4.x, a4.y, a4.z, a4.w};
    float bv[4] = {c4v.x, c4v.y, c4v.z, c4v.w};
#pragma unroll
    for (int j = 0; j < 4; ++j) {
      int k = k4 * 4 + j;
#pragma unroll
      for (int c4 = 0; c4 < 10; ++c4) {
        float4 w = *(const float4*)&Wl[k * 40 + c4 * 4];  // uniform -> broadcast
        acc0[c4 * 4 + 0] = fmaf(av[j], w.x, acc0[c4 * 4 + 0]);
        acc0[c4 * 4 + 1] = fmaf(av[j], w.y, acc0[c4 * 4 + 1]);
        acc0[c4 * 4 + 2] = fmaf(av[j], w.z, acc0[c4 * 4 + 2]);
        acc0[c4 * 4 + 3] = fmaf(av[j], w.w, acc0[c4 * 4 + 3]);
        acc1[c4 * 4 + 0] = fmaf(bv[j], w.x, acc1[c4 * 4 + 0]);
        acc1[c4 * 4 + 1] = fmaf(bv[j], w.y, acc1[c4 * 4 + 1]);
        acc1[c4 * 4 + 2] = fmaf(bv[j], w.z, acc1[c4 * 4 + 2]);
        acc1[c4 * 4 + 3] = fmaf(bv[j], w.w, acc1[c4 * 4 + 3]);
      }
    }
  }
  float m0 = acc0[0], m1 = acc1[0];
#pragma unroll
  for (int c = 1; c < 40; ++c) { m0 = fmaxf(m0, acc0[c]); m1 = fmaxf(m1, acc1[c]); }
  float s0 = 0.f, s1 = 0.f;
#pragma unroll
  for (int c = 0; c < 40; ++c) { s0 += expf(acc0[c] - m0); s1 += expf(acc1[c] - m1); }
  float l0 = m0 + logf(s0);
  float l1 = m1 + logf(s1);
#pragma unroll
  for (int c4 = 0; c4 < 10; ++c4) {
    if (ok0) {
      float4 o = make_float4(acc0[c4 * 4 + 0] - l0, acc0[c4 * 4 + 1] - l0,
                             acc0[c4 * 4 + 2] - l0, acc0[c4 * 4 + 3] - l0);
      *(float4*)&out[(size_t)n0 * 40 + c4 * 4] = o;
    }
    if (ok1) {
      float4 o = make_float4(acc1[c4 * 4 + 0] - l1, acc1[c4 * 4 + 1] - l1,
                             acc1[c4 * 4 + 2] - l1, acc1[c4 * 4 + 3] - l1);
      *(float4*)&out[(size_t)n1 * 40 + c4 * 4] = o;
    }
  }
}

// ---------- launch ----------
extern "C" void kernel_launch(void* const* d_in, const int* in_sizes, int n_in,
                              void* d_out, int out_size, void* d_ws, size_t ws_size,
                              hipStream_t stream) {
  const float* x  = (const float*)d_in[0];
  const int*   ei = (const int*)d_in[1];
  const float* W1 = (const float*)d_in[2];
  const float* b1 = (const float*)d_in[3];
  const float* g1 = (const float*)d_in[4];
  const float* t1 = (const float*)d_in[5];
  const float* W2 = (const float*)d_in[6];
  const float* b2 = (const float*)d_in[7];
  const float* g2 = (const float*)d_in[8];
  const float* t2 = (const float*)d_in[9];
  const float* W3 = (const float*)d_in[10];
  const float* b3 = (const float*)d_in[11];
  const float* g3 = (const float*)d_in[12];
  const float* t3 = (const float*)d_in[13];
  const float* Wf = (const float*)d_in[14];
  const float* bf = (const float*)d_in[15];
  float* out = (float*)d_out;

  const int N = in_sizes[0] / 128;
  const int E = in_sizes[1] / 2;
  const int* src = ei;
  const int* dst = ei + E;
  const int NBUK = (N + 127) >> GRP_SHIFT;
  const int NEB  = (E + PCHUNK - 1) / PCHUNK;
  const int ZOFF = N * 128;  // byte offset of the zero row in hs

  char* p = (char*)d_ws;
  auto carve = [&](size_t bytes) -> char* {
    char* r = p;
    p += (bytes + 255) & ~(size_t)255;
    return r;
  };
  int*      bcnt    = (int*)carve((size_t)(NBUK + 1) * 4);  // +1 = gcur
  int*      gcur    = bcnt + NBUK;
  unsigned* pairs   = (unsigned*)carve((size_t)NBUK * BCAP * 4);
  int*      csr     = (int*)carve(((size_t)E + 15 * (size_t)N + 256) * 4);
  int2*     noff    = (int2*)carve((size_t)N * 8);
  float*    dinv    = (float*)carve((size_t)N * 4);
  unsigned short* hs = (unsigned short*)carve(((size_t)N * 64 + 64) * 2);  // +1 zero row
  float*    hA      = (float*)carve((size_t)N * 64 * 4);
  float*    hB      = (float*)carve((size_t)N * 64 * 4);
  (void)ws_size; (void)n_in; (void)out_size;

  dim3 B(256);
  dim3 B1K(1024);
  (void)hipMemsetAsync(bcnt, 0, (size_t)(NBUK + 1) * 4, stream);   // bcnt + gcur
  (void)hipMemsetAsync(hs + (size_t)N * 64, 0, 128, stream);       // zero row
  k_partition<<<dim3(NEB), B1K, 0, stream>>>(src, dst, bcnt, pairs, E, NBUK);
  k_bucket_place<<<dim3(NBUK), B, 0, stream>>>(pairs, bcnt, gcur, noff, dinv, csr, N, ZOFF);

  const int GB = (N + 63) / 64;
  const int GA = (N + 3) / 4;
  const int GF = (N + 511) / 512;
  // layer 1
  gemm_scale<128><<<dim3(GB), B, 0, stream>>>(x, W1, dinv, hs, N);
  k_agg<<<dim3(GA), B, 0, stream>>>((const char*)hs, (const uint4*)csr, noff, dinv, b1, g1, t1, hA, N);
  // layer 2
  gemm_scale<64><<<dim3(GB), B, 0, stream>>>(hA, W2, dinv, hs, N);
  k_agg<<<dim3(GA), B, 0, stream>>>((const char*)hs, (const uint4*)csr, noff, dinv, b2, g2, t2, hB, N);
  // layer 3
  gemm_scale<64><<<dim3(GB), B, 0, stream>>>(hB, W3, dinv, hs, N);
  k_agg<<<dim3(GA), B, 0, stream>>>((const char*)hs, (const uint4*)csr, noff, dinv, b3, g3, t3, hA, N);
  // final projection + log_softmax
  k_final<<<dim3(GF), B, 0, stream>>>(hA, Wf, bf, out, N);
}

// Round 14
// 275.773 us; speedup vs baseline: 1.0513x; 1.0044x over previous
//
#include <hip/hip_runtime.h>
#include <math.h>
#include <stdint.h>

#define LN_EPS 1e-5f
#define GRP_SHIFT 7           // 128 nodes per bucket
#define MAXBUK 1024           // N <= 131072
#define PCHUNK 8192           // edges per partition block (1024 threads x 8)
#define BCAP 4096             // fixed per-bucket capacity (mean 2048, huge margin)

// ---------- bf16 helpers (RNE) ----------
__device__ __forceinline__ unsigned short f2bf(float f) {
  unsigned int u = __float_as_uint(f);
  unsigned int r = u + 0x7fffu + ((u >> 16) & 1u);
  return (unsigned short)(r >> 16);
}
__device__ __forceinline__ float bfLo(unsigned v) { return __uint_as_float(v << 16); }
__device__ __forceinline__ float bfHi(unsigned v) { return __uint_as_float(v & 0xffff0000u); }

// ---------- CSR build: single-pass partition into fixed-capacity buckets ----------
// payload packed (src<<7)|dst_local (N < 2^25); per-(block,bucket) rank from LDS hist.
__global__ __launch_bounds__(1024) void k_partition(const int* __restrict__ src,
                                                    const int* __restrict__ dst,
                                                    int* __restrict__ bcnt,
                                                    unsigned* __restrict__ pairs, int E, int NB) {
  __shared__ int hist[MAXBUK];
  __shared__ int base[MAXBUK];
  int t = threadIdx.x;
  for (int i = t; i < NB; i += 1024) hist[i] = 0;
  __syncthreads();
  int e0 = blockIdx.x * PCHUNK;
  int e1 = min(e0 + PCHUNK, E);
  int sv[8], dv[8], rk[8];
#pragma unroll
  for (int j = 0; j < 8; ++j) {
    int i = e0 + t + j * 1024;
    if (i < e1) {
      sv[j] = src[i];
      dv[j] = dst[i];
      rk[j] = atomicAdd(&hist[dv[j] >> GRP_SHIFT], 1);
    } else {
      dv[j] = -1;
    }
  }
  __syncthreads();
  for (int i = t; i < NB; i += 1024) {
    int c = hist[i];
    base[i] = c ? (i * BCAP + atomicAdd(&bcnt[i], c)) : 0;
  }
  __syncthreads();
#pragma unroll
  for (int j = 0; j < 8; ++j) {
    if (dv[j] >= 0) {
      int b = dv[j] >> GRP_SHIFT;
      pairs[base[b] + rk[j]] = ((unsigned)sv[j] << GRP_SHIFT) | (unsigned)(dv[j] & 127);
    }
  }
}

// per-bucket: degrees (LDS), 16-aligned per-node slots funded by a global atomic
// cursor; csr holds BYTE offsets (src*128), pad slots hold ZOFF (zero row).
// block 0 also zeroes the hs zero-row (replaces a memset dispatch).
__global__ __launch_bounds__(256) void k_bucket_place(const unsigned* __restrict__ pairs,
                                                      const int* __restrict__ bcnt,
                                                      int* __restrict__ gcur,
                                                      int2* __restrict__ noff,
                                                      float* __restrict__ dinv,
                                                      int* __restrict__ csr,
                                                      unsigned* __restrict__ zrow,
                                                      int N, int ZOFF) {
  __shared__ int cnt[128];
  __shared__ int sc[128];
  __shared__ int sbase;
  int t = threadIdx.x;
  int b = blockIdx.x;
  int node0 = b << GRP_SHIFT;
  if (b == 0 && t < 32) zrow[t] = 0u;   // zero row of hs (128 B)
  if (t < 128) cnt[t] = 0;
  int beg = b * BCAP;
  int end = beg + bcnt[b];
  __syncthreads();
  for (int i = beg + t; i < end; i += 256) atomicAdd(&cnt[pairs[i] & 127u], 1);
  __syncthreads();
  int pcnt = 0;
  if (t < 128) { pcnt = (cnt[t] + 15) & ~15; sc[t] = pcnt; }
  __syncthreads();
  for (int o = 1; o < 128; o <<= 1) {
    int x = (t < 128 && t >= o) ? sc[t - o] : 0;
    __syncthreads();
    if (t < 128) sc[t] += x;
    __syncthreads();
  }
  if (t == 127) sbase = atomicAdd(gcur, sc[127]);
  __syncthreads();
  if (t < 128) {
    int off = sbase + sc[t] - pcnt;
    int node = node0 + t;
    if (node < N) {
      int d = cnt[t];
      noff[node] = make_int2(off, off + d);
      dinv[node] = d > 0 ? rsqrtf((float)d) : 0.f;
      for (int i = off + d; i < off + pcnt; ++i) csr[i] = ZOFF;  // zero-row pads
    }
    sc[t] = off;  // becomes write cursor
  }
  __syncthreads();
  for (int i = beg + t; i < end; i += 256) {
    unsigned pk = pairs[i];
    int pos = atomicAdd(&sc[pk & 127u], 1);
    csr[pos] = (int)(pk & ~127u);  // src*128 byte offset
  }
}

// ---------- GEMM: out[m] = bf16( dinv[m] * (A[m] @ W) ), A:[M][K] f32, W:[K][64] ----------
template <int K>
__global__ __launch_bounds__(256) void gemm_scale(const float* __restrict__ A,
                                                  const float* __restrict__ W,
                                                  const float* __restrict__ dinv,
                                                  unsigned short* __restrict__ out, int M) {
  __shared__ float xs[16][64];   // transposed A tile: xs[k][m]
  __shared__ float wsh[16][64];  // W tile: wsh[k][c]
  int t = threadIdx.x;
  int m0 = blockIdx.x * 64;
  int lm = t >> 2;
  int lk = (t & 3) << 2;
  int mr = (t & 15) << 2;
  int cc = (t >> 4) << 2;
  float acc[4][4] = {{0.f}};
  int gm = m0 + lm;
  const bool mok = gm < M;
  for (int kc = 0; kc < K; kc += 16) {
    float4 av = make_float4(0.f, 0.f, 0.f, 0.f);
    if (mok) av = *(const float4*)&A[(size_t)gm * K + kc + lk];
    float wv[4];
#pragma unroll
    for (int r = 0; r < 4; ++r) {
      int k = (t >> 6) + (r << 2);
      wv[r] = W[(size_t)(kc + k) * 64 + (t & 63)];
    }
    __syncthreads();
    xs[lk + 0][lm] = av.x;
    xs[lk + 1][lm] = av.y;
    xs[lk + 2][lm] = av.z;
    xs[lk + 3][lm] = av.w;
#pragma unroll
    for (int r = 0; r < 4; ++r) {
      int k = (t >> 6) + (r << 2);
      wsh[k][t & 63] = wv[r];
    }
    __syncthreads();
#pragma unroll
    for (int k = 0; k < 16; ++k) {
      float4 a4 = *(const float4*)&xs[k][mr];
      float4 b4 = *(const float4*)&wsh[k][cc];
      float a[4] = {a4.x, a4.y, a4.z, a4.w};
      float b[4] = {b4.x, b4.y, b4.z, b4.w};
#pragma unroll
      for (int i = 0; i < 4; ++i)
#pragma unroll
        for (int j = 0; j < 4; ++j) acc[i][j] = fmaf(a[i], b[j], acc[i][j]);
    }
  }
#pragma unroll
  for (int i = 0; i < 4; ++i) {
    int row = m0 + mr + i;
    if (row < M) {
      float sc = dinv[row];
      ushort4 o;
      o.x = f2bf(acc[i][0] * sc);
      o.y = f2bf(acc[i][1] * sc);
      o.z = f2bf(acc[i][2] * sc);
      o.w = f2bf(acc[i][3] * sc);
      *(ushort4*)&out[(size_t)row * 64 + cc] = o;
    }
  }
}

// ---------- aggregation + bias + LayerNorm + ReLU (proven floor structure) ----------
// Processes nodes [nbase, nlimit). wave per node; lane = (q = lane>>4, fl = lane&15).
__global__ __launch_bounds__(256) void k_agg(const char* __restrict__ hsb,
                                             const uint4* __restrict__ csr4,
                                             const int2* __restrict__ noff,
                                             const float* __restrict__ dinv,
                                             const float* __restrict__ b,
                                             const float* __restrict__ g,
                                             const float* __restrict__ tt,
                                             float* __restrict__ out, int nbase, int nlimit) {
  int lane = threadIdx.x & 63;
  int q = lane >> 4;
  int fl = lane & 15;
  int node = nbase + blockIdx.x * 4 + (threadIdx.x >> 6);
  if (node >= nlimit) return;
  int2 be = noff[node];
  int ng = (be.y - be.x + 15) >> 4;   // 16-edge groups (padded slot)
  float a0 = 0.f, a1 = 0.f, a2 = 0.f, a3 = 0.f;
  unsigned fo = (unsigned)fl * 8u;
  int c4 = (be.x >> 2) + q;
  for (; ng > 0; --ng, c4 += 4) {
    uint4 iv = csr4[c4];                 // this lane's 4 edges (byte offsets)
    uint2 w0 = *(const uint2*)(hsb + (iv.x + fo));
    uint2 w1 = *(const uint2*)(hsb + (iv.y + fo));
    uint2 w2 = *(const uint2*)(hsb + (iv.z + fo));
    uint2 w3 = *(const uint2*)(hsb + (iv.w + fo));
    a0 += bfLo(w0.x); a1 += bfHi(w0.x); a2 += bfLo(w0.y); a3 += bfHi(w0.y);
    a0 += bfLo(w1.x); a1 += bfHi(w1.x); a2 += bfLo(w1.y); a3 += bfHi(w1.y);
    a0 += bfLo(w2.x); a1 += bfHi(w2.x); a2 += bfLo(w2.y); a3 += bfHi(w2.y);
    a0 += bfLo(w3.x); a1 += bfHi(w3.x); a2 += bfLo(w3.y); a3 += bfHi(w3.y);
  }

  // combine the 4 quarters (independent 2-step chains)
  a0 += __shfl_xor(a0, 16, 64); a0 += __shfl_xor(a0, 32, 64);
  a1 += __shfl_xor(a1, 16, 64); a1 += __shfl_xor(a1, 32, 64);
  a2 += __shfl_xor(a2, 16, 64); a2 += __shfl_xor(a2, 32, 64);
  a3 += __shfl_xor(a3, 16, 64); a3 += __shfl_xor(a3, 32, 64);

  float dv = dinv[node];
  float4 bb = *(const float4*)&b[fl * 4];
  float v0 = fmaf(a0, dv, bb.x);
  float v1 = fmaf(a1, dv, bb.y);
  float v2 = fmaf(a2, dv, bb.z);
  float v3 = fmaf(a3, dv, bb.w);
  float s  = v0 + v1 + v2 + v3;
  float s2 = fmaf(v0, v0, fmaf(v1, v1, fmaf(v2, v2, v3 * v3)));
#pragma unroll
  for (int m = 1; m < 16; m <<= 1) {   // two independent 4-step chains
    s  += __shfl_xor(s, m, 64);
    s2 += __shfl_xor(s2, m, 64);
  }
  float mu = s * 0.015625f;            // /64
  float var = fmaxf(s2 * 0.015625f - mu * mu, 0.f);
  float rs = rsqrtf(var + LN_EPS);
  float4 gg = *(const float4*)&g[fl * 4];
  float4 t4 = *(const float4*)&tt[fl * 4];
  if (q == 0) {
    float4 o;
    o.x = fmaxf(fmaf(gg.x * (v0 - mu), rs, t4.x), 0.f);
    o.y = fmaxf(fmaf(gg.y * (v1 - mu), rs, t4.y), 0.f);
    o.z = fmaxf(fmaf(gg.z * (v2 - mu), rs, t4.z), 0.f);
    o.w = fmaxf(fmaf(gg.w * (v3 - mu), rs, t4.w), 0.f);
    *(float4*)&out[(size_t)node * 64 + fl * 4] = o;
  }
}

// ---------- final: logits = h @ Wf + bf ; log_softmax (1 node/thread) ----------
__global__ __launch_bounds__(256) void k_final(const float* __restrict__ h,
                                               const float* __restrict__ Wf,
                                               const float* __restrict__ bf,
                                               float* __restrict__ out, int n) {
  __shared__ float Wl[64 * 40];
  __shared__ float bl[40];
  int t = threadIdx.x;
  for (int i = t; i < 64 * 40; i += 256) Wl[i] = Wf[i];
  if (t < 40) bl[t] = bf[t];
  __syncthreads();
  int n0 = blockIdx.x * 256 + t;
  if (n0 >= n) return;
  float acc[40];
#pragma unroll
  for (int c = 0; c < 40; ++c) acc[c] = bl[c];
  const float* h0 = &h[(size_t)n0 * 64];
#pragma unroll 2
  for (int k4 = 0; k4 < 16; ++k4) {
    float4 a4 = *(const float4*)&h0[k4 * 4];
    float av[4] = {a4.x, a4.y, a4.z, a4.w};
#pragma unroll
    for (int j = 0; j < 4; ++j) {
      int k = k4 * 4 + j;
#pragma unroll
      for (int c4 = 0; c4 < 10; ++c4) {
        float4 w = *(const float4*)&Wl[k * 40 + c4 * 4];  // uniform -> broadcast
        acc[c4 * 4 + 0] = fmaf(av[j], w.x, acc[c4 * 4 + 0]);
        acc[c4 * 4 + 1] = fmaf(av[j], w.y, acc[c4 * 4 + 1]);
        acc[c4 * 4 + 2] = fmaf(av[j], w.z, acc[c4 * 4 + 2]);
        acc[c4 * 4 + 3] = fmaf(av[j], w.w, acc[c4 * 4 + 3]);
      }
    }
  }
  float m0 = acc[0];
#pragma unroll
  for (int c = 1; c < 40; ++c) m0 = fmaxf(m0, acc[c]);
  float s0 = 0.f;
#pragma unroll
  for (int c = 0; c < 40; ++c) s0 += expf(acc[c] - m0);
  float l0 = m0 + logf(s0);
#pragma unroll
  for (int c4 = 0; c4 < 10; ++c4) {
    float4 o = make_float4(acc[c4 * 4 + 0] - l0, acc[c4 * 4 + 1] - l0,
                           acc[c4 * 4 + 2] - l0, acc[c4 * 4 + 3] - l0);
    *(float4*)&out[(size_t)n0 * 40 + c4 * 4] = o;
  }
}

// ---------- launch ----------
extern "C" void kernel_launch(void* const* d_in, const int* in_sizes, int n_in,
                              void* d_out, int out_size, void* d_ws, size_t ws_size,
                              hipStream_t stream) {
  const float* x  = (const float*)d_in[0];
  const int*   ei = (const int*)d_in[1];
  const float* W1 = (const float*)d_in[2];
  const float* b1 = (const float*)d_in[3];
  const float* g1 = (const float*)d_in[4];
  const float* t1 = (const float*)d_in[5];
  const float* W2 = (const float*)d_in[6];
  const float* b2 = (const float*)d_in[7];
  const float* g2 = (const float*)d_in[8];
  const float* t2 = (const float*)d_in[9];
  const float* W3 = (const float*)d_in[10];
  const float* b3 = (const float*)d_in[11];
  const float* g3 = (const float*)d_in[12];
  const float* t3 = (const float*)d_in[13];
  const float* Wf = (const float*)d_in[14];
  const float* bf = (const float*)d_in[15];
  float* out = (float*)d_out;

  const int N = in_sizes[0] / 128;
  const int E = in_sizes[1] / 2;
  const int* src = ei;
  const int* dst = ei + E;
  const int NBUK = (N + 127) >> GRP_SHIFT;
  const int NEB  = (E + PCHUNK - 1) / PCHUNK;
  const int ZOFF = N * 128;  // byte offset of the zero row in hs

  char* p = (char*)d_ws;
  auto carve = [&](size_t bytes) -> char* {
    char* r = p;
    p += (bytes + 255) & ~(size_t)255;
    return r;
  };
  int*      bcnt    = (int*)carve((size_t)(NBUK + 1) * 4);  // +1 = gcur
  int*      gcur    = bcnt + NBUK;
  unsigned* pairs   = (unsigned*)carve((size_t)NBUK * BCAP * 4);
  int*      csr     = (int*)carve(((size_t)E + 15 * (size_t)N + 256) * 4);
  int2*     noff    = (int2*)carve((size_t)N * 8);
  float*    dinv    = (float*)carve((size_t)N * 4);
  unsigned short* hs = (unsigned short*)carve(((size_t)N * 64 + 64) * 2);  // +1 zero row
  float*    hA      = (float*)carve((size_t)N * 64 * 4);
  float*    hB      = (float*)carve((size_t)N * 64 * 4);
  (void)ws_size; (void)n_in; (void)out_size;

  dim3 B(256);
  dim3 B1K(1024);
  (void)hipMemsetAsync(bcnt, 0, (size_t)(NBUK + 1) * 4, stream);   // bcnt + gcur
  k_partition<<<dim3(NEB), B1K, 0, stream>>>(src, dst, bcnt, pairs, E, NBUK);
  k_bucket_place<<<dim3(NBUK), B, 0, stream>>>(pairs, bcnt, gcur, noff, dinv, csr,
                                               (unsigned*)(hs + (size_t)N * 64), N, ZOFF);

  const int GB = (N + 63) / 64;
  const int H  = ((N / 2) + 3) & ~3;          // half-split point (multiple of 4)
  const int GA1 = (H + 3) / 4;
  const int GA2 = (N - H + 3) / 4;
  const int GF = (N + 255) / 256;
  const char* hsc = (const char*)hs;
  const uint4* c4p = (const uint4*)csr;
  // layer 1
  gemm_scale<128><<<dim3(GB), B, 0, stream>>>(x, W1, dinv, hs, N);
  k_agg<<<dim3(GA1), B, 0, stream>>>(hsc, c4p, noff, dinv, b1, g1, t1, hA, 0, H);
  k_agg<<<dim3(GA2), B, 0, stream>>>(hsc, c4p, noff, dinv, b1, g1, t1, hA, H, N);
  // layer 2
  gemm_scale<64><<<dim3(GB), B, 0, stream>>>(hA, W2, dinv, hs, N);
  k_agg<<<dim3(GA1), B, 0, stream>>>(hsc, c4p, noff, dinv, b2, g2, t2, hB, 0, H);
  k_agg<<<dim3(GA2), B, 0, stream>>>(hsc, c4p, noff, dinv, b2, g2, t2, hB, H, N);
  // layer 3
  gemm_scale<64><<<dim3(GB), B, 0, stream>>>(hB, W3, dinv, hs, N);
  k_agg<<<dim3(GA1), B, 0, stream>>>(hsc, c4p, noff, dinv, b3, g3, t3, hA, 0, H);
  k_agg<<<dim3(GA2), B, 0, stream>>>(hsc, c4p, noff, dinv, b3, g3, t3, hA, H, N);
  // final projection + log_softmax
  k_final<<<dim3(GF), B, 0, stream>>>(hA, Wf, bf, out, N);
}

// Round 15
// 272.078 us; speedup vs baseline: 1.0656x; 1.0136x over previous
//
#include <hip/hip_runtime.h>
#include <math.h>
#include <stdint.h>

#define LN_EPS 1e-5f
#define GRP_SHIFT 7           // 128 nodes per bucket
#define MAXBUK 1024           // N <= 131072
#define PCHUNK 8192           // edges per partition block (1024 threads x 8)
#define BCAP 4096             // fixed per-bucket capacity (mean 2048, huge margin)

// ---------- bf16 helpers (RNE) ----------
__device__ __forceinline__ unsigned short f2bf(float f) {
  unsigned int u = __float_as_uint(f);
  unsigned int r = u + 0x7fffu + ((u >> 16) & 1u);
  return (unsigned short)(r >> 16);
}
__device__ __forceinline__ float bfLo(unsigned v) { return __uint_as_float(v << 16); }
__device__ __forceinline__ float bfHi(unsigned v) { return __uint_as_float(v & 0xffff0000u); }

// ---------- CSR build: single-pass partition into fixed-capacity buckets ----------
// payload packed (src<<7)|dst_local (N < 2^25); per-(block,bucket) rank from LDS hist.
__global__ __launch_bounds__(1024) void k_partition(const int* __restrict__ src,
                                                    const int* __restrict__ dst,
                                                    int* __restrict__ bcnt,
                                                    unsigned* __restrict__ pairs, int E, int NB) {
  __shared__ int hist[MAXBUK];
  __shared__ int base[MAXBUK];
  int t = threadIdx.x;
  for (int i = t; i < NB; i += 1024) hist[i] = 0;
  __syncthreads();
  int e0 = blockIdx.x * PCHUNK;
  int e1 = min(e0 + PCHUNK, E);
  int sv[8], dv[8], rk[8];
#pragma unroll
  for (int j = 0; j < 8; ++j) {
    int i = e0 + t + j * 1024;
    if (i < e1) {
      sv[j] = src[i];
      dv[j] = dst[i];
      rk[j] = atomicAdd(&hist[dv[j] >> GRP_SHIFT], 1);
    } else {
      dv[j] = -1;
    }
  }
  __syncthreads();
  for (int i = t; i < NB; i += 1024) {
    int c = hist[i];
    base[i] = c ? (i * BCAP + atomicAdd(&bcnt[i], c)) : 0;
  }
  __syncthreads();
#pragma unroll
  for (int j = 0; j < 8; ++j) {
    if (dv[j] >= 0) {
      int b = dv[j] >> GRP_SHIFT;
      pairs[base[b] + rk[j]] = ((unsigned)sv[j] << GRP_SHIFT) | (unsigned)(dv[j] & 127);
    }
  }
}

// per-bucket: degrees (LDS), 16-aligned per-node slots funded by a global atomic
// cursor; csr holds BYTE offsets (src*128), pad slots hold ZOFF (zero row).
// block 0 also zeroes the hs zero-row (replaces a memset dispatch).
__global__ __launch_bounds__(256) void k_bucket_place(const unsigned* __restrict__ pairs,
                                                      const int* __restrict__ bcnt,
                                                      int* __restrict__ gcur,
                                                      int2* __restrict__ noff,
                                                      float* __restrict__ dinv,
                                                      int* __restrict__ csr,
                                                      unsigned* __restrict__ zrow,
                                                      int N, int ZOFF) {
  __shared__ int cnt[128];
  __shared__ int sc[128];
  __shared__ int sbase;
  int t = threadIdx.x;
  int b = blockIdx.x;
  int node0 = b << GRP_SHIFT;
  if (b == 0 && t < 32) zrow[t] = 0u;   // zero row of hs (128 B)
  if (t < 128) cnt[t] = 0;
  int beg = b * BCAP;
  int end = beg + bcnt[b];
  __syncthreads();
  for (int i = beg + t; i < end; i += 256) atomicAdd(&cnt[pairs[i] & 127u], 1);
  __syncthreads();
  int pcnt = 0;
  if (t < 128) { pcnt = (cnt[t] + 15) & ~15; sc[t] = pcnt; }
  __syncthreads();
  for (int o = 1; o < 128; o <<= 1) {
    int x = (t < 128 && t >= o) ? sc[t - o] : 0;
    __syncthreads();
    if (t < 128) sc[t] += x;
    __syncthreads();
  }
  if (t == 127) sbase = atomicAdd(gcur, sc[127]);
  __syncthreads();
  if (t < 128) {
    int off = sbase + sc[t] - pcnt;
    int node = node0 + t;
    if (node < N) {
      int d = cnt[t];
      noff[node] = make_int2(off, off + d);
      dinv[node] = d > 0 ? rsqrtf((float)d) : 0.f;
      for (int i = off + d; i < off + pcnt; ++i) csr[i] = ZOFF;  // zero-row pads
    }
    sc[t] = off;  // becomes write cursor
  }
  __syncthreads();
  for (int i = beg + t; i < end; i += 256) {
    unsigned pk = pairs[i];
    int pos = atomicAdd(&sc[pk & 127u], 1);
    csr[pos] = (int)(pk & ~127u);  // src*128 byte offset
  }
}

// ---------- GEMM: out[m] = bf16( dinv[m] * (A[m] @ W) ), A:[M][K] f32, W:[K][64] ----------
template <int K>
__global__ __launch_bounds__(256) void gemm_scale(const float* __restrict__ A,
                                                  const float* __restrict__ W,
                                                  const float* __restrict__ dinv,
                                                  unsigned short* __restrict__ out, int M) {
  __shared__ float xs[16][64];   // transposed A tile: xs[k][m]
  __shared__ float wsh[16][64];  // W tile: wsh[k][c]
  int t = threadIdx.x;
  int m0 = blockIdx.x * 64;
  int lm = t >> 2;
  int lk = (t & 3) << 2;
  int mr = (t & 15) << 2;
  int cc = (t >> 4) << 2;
  float acc[4][4] = {{0.f}};
  int gm = m0 + lm;
  const bool mok = gm < M;
  for (int kc = 0; kc < K; kc += 16) {
    float4 av = make_float4(0.f, 0.f, 0.f, 0.f);
    if (mok) av = *(const float4*)&A[(size_t)gm * K + kc + lk];
    float wv[4];
#pragma unroll
    for (int r = 0; r < 4; ++r) {
      int k = (t >> 6) + (r << 2);
      wv[r] = W[(size_t)(kc + k) * 64 + (t & 63)];
    }
    __syncthreads();
    xs[lk + 0][lm] = av.x;
    xs[lk + 1][lm] = av.y;
    xs[lk + 2][lm] = av.z;
    xs[lk + 3][lm] = av.w;
#pragma unroll
    for (int r = 0; r < 4; ++r) {
      int k = (t >> 6) + (r << 2);
      wsh[k][t & 63] = wv[r];
    }
    __syncthreads();
#pragma unroll
    for (int k = 0; k < 16; ++k) {
      float4 a4 = *(const float4*)&xs[k][mr];
      float4 b4 = *(const float4*)&wsh[k][cc];
      float a[4] = {a4.x, a4.y, a4.z, a4.w};
      float b[4] = {b4.x, b4.y, b4.z, b4.w};
#pragma unroll
      for (int i = 0; i < 4; ++i)
#pragma unroll
        for (int j = 0; j < 4; ++j) acc[i][j] = fmaf(a[i], b[j], acc[i][j]);
    }
  }
#pragma unroll
  for (int i = 0; i < 4; ++i) {
    int row = m0 + mr + i;
    if (row < M) {
      float sc = dinv[row];
      ushort4 o;
      o.x = f2bf(acc[i][0] * sc);
      o.y = f2bf(acc[i][1] * sc);
      o.z = f2bf(acc[i][2] * sc);
      o.w = f2bf(acc[i][3] * sc);
      *(ushort4*)&out[(size_t)row * 64 + cc] = o;
    }
  }
}

// ---------- aggregation + bias + LayerNorm + ReLU (proven floor structure) ----------
// 8 nodes per 512-thread block; wave per node; lane = (q = lane>>4, fl = lane&15).
// csr holds byte offsets in 16-aligned, zero-row-padded slots -> branch/mask/shuffle-free
// inner loop: 1 uint4 idx load + 4 gathers per 16 edges.
__global__ __launch_bounds__(512) void k_agg(const char* __restrict__ hsb,
                                             const uint4* __restrict__ csr4,
                                             const int2* __restrict__ noff,
                                             const float* __restrict__ dinv,
                                             const float* __restrict__ b,
                                             const float* __restrict__ g,
                                             const float* __restrict__ tt,
                                             float* __restrict__ out, int n) {
  int lane = threadIdx.x & 63;
  int q = lane >> 4;
  int fl = lane & 15;
  int node = blockIdx.x * 8 + (threadIdx.x >> 6);
  if (node >= n) return;
  int2 be = noff[node];
  int ng = (be.y - be.x + 15) >> 4;   // 16-edge groups (padded slot)
  float a0 = 0.f, a1 = 0.f, a2 = 0.f, a3 = 0.f;
  unsigned fo = (unsigned)fl * 8u;
  int c4 = (be.x >> 2) + q;
  for (; ng > 0; --ng, c4 += 4) {
    uint4 iv = csr4[c4];                 // this lane's 4 edges (byte offsets)
    uint2 w0 = *(const uint2*)(hsb + (iv.x + fo));
    uint2 w1 = *(const uint2*)(hsb + (iv.y + fo));
    uint2 w2 = *(const uint2*)(hsb + (iv.z + fo));
    uint2 w3 = *(const uint2*)(hsb + (iv.w + fo));
    a0 += bfLo(w0.x); a1 += bfHi(w0.x); a2 += bfLo(w0.y); a3 += bfHi(w0.y);
    a0 += bfLo(w1.x); a1 += bfHi(w1.x); a2 += bfLo(w1.y); a3 += bfHi(w1.y);
    a0 += bfLo(w2.x); a1 += bfHi(w2.x); a2 += bfLo(w2.y); a3 += bfHi(w2.y);
    a0 += bfLo(w3.x); a1 += bfHi(w3.x); a2 += bfLo(w3.y); a3 += bfHi(w3.y);
  }

  // combine the 4 quarters (independent 2-step chains)
  a0 += __shfl_xor(a0, 16, 64); a0 += __shfl_xor(a0, 32, 64);
  a1 += __shfl_xor(a1, 16, 64); a1 += __shfl_xor(a1, 32, 64);
  a2 += __shfl_xor(a2, 16, 64); a2 += __shfl_xor(a2, 32, 64);
  a3 += __shfl_xor(a3, 16, 64); a3 += __shfl_xor(a3, 32, 64);

  float dv = dinv[node];
  float4 bb = *(const float4*)&b[fl * 4];
  float v0 = fmaf(a0, dv, bb.x);
  float v1 = fmaf(a1, dv, bb.y);
  float v2 = fmaf(a2, dv, bb.z);
  float v3 = fmaf(a3, dv, bb.w);
  float s  = v0 + v1 + v2 + v3;
  float s2 = fmaf(v0, v0, fmaf(v1, v1, fmaf(v2, v2, v3 * v3)));
#pragma unroll
  for (int m = 1; m < 16; m <<= 1) {   // two independent 4-step chains
    s  += __shfl_xor(s, m, 64);
    s2 += __shfl_xor(s2, m, 64);
  }
  float mu = s * 0.015625f;            // /64
  float var = fmaxf(s2 * 0.015625f - mu * mu, 0.f);
  float rs = rsqrtf(var + LN_EPS);
  float4 gg = *(const float4*)&g[fl * 4];
  float4 t4 = *(const float4*)&tt[fl * 4];
  if (q == 0) {
    float4 o;
    o.x = fmaxf(fmaf(gg.x * (v0 - mu), rs, t4.x), 0.f);
    o.y = fmaxf(fmaf(gg.y * (v1 - mu), rs, t4.y), 0.f);
    o.z = fmaxf(fmaf(gg.z * (v2 - mu), rs, t4.z), 0.f);
    o.w = fmaxf(fmaf(gg.w * (v3 - mu), rs, t4.w), 0.f);
    *(float4*)&out[(size_t)node * 64 + fl * 4] = o;
  }
}

// ---------- final: logits = h @ Wf + bf ; log_softmax (1 node/thread) ----------
__global__ __launch_bounds__(256) void k_final(const float* __restrict__ h,
                                               const float* __restrict__ Wf,
                                               const float* __restrict__ bf,
                                               float* __restrict__ out, int n) {
  __shared__ float Wl[64 * 40];
  __shared__ float bl[40];
  int t = threadIdx.x;
  for (int i = t; i < 64 * 40; i += 256) Wl[i] = Wf[i];
  if (t < 40) bl[t] = bf[t];
  __syncthreads();
  int n0 = blockIdx.x * 256 + t;
  if (n0 >= n) return;
  float acc[40];
#pragma unroll
  for (int c = 0; c < 40; ++c) acc[c] = bl[c];
  const float* h0 = &h[(size_t)n0 * 64];
#pragma unroll 2
  for (int k4 = 0; k4 < 16; ++k4) {
    float4 a4 = *(const float4*)&h0[k4 * 4];
    float av[4] = {a4.x, a4.y, a4.z, a4.w};
#pragma unroll
    for (int j = 0; j < 4; ++j) {
      int k = k4 * 4 + j;
#pragma unroll
      for (int c4 = 0; c4 < 10; ++c4) {
        float4 w = *(const float4*)&Wl[k * 40 + c4 * 4];  // uniform -> broadcast
        acc[c4 * 4 + 0] = fmaf(av[j], w.x, acc[c4 * 4 + 0]);
        acc[c4 * 4 + 1] = fmaf(av[j], w.y, acc[c4 * 4 + 1]);
        acc[c4 * 4 + 2] = fmaf(av[j], w.z, acc[c4 * 4 + 2]);
        acc[c4 * 4 + 3] = fmaf(av[j], w.w, acc[c4 * 4 + 3]);
      }
    }
  }
  float m0 = acc[0];
#pragma unroll
  for (int c = 1; c < 40; ++c) m0 = fmaxf(m0, acc[c]);
  float s0 = 0.f;
#pragma unroll
  for (int c = 0; c < 40; ++c) s0 += expf(acc[c] - m0);
  float l0 = m0 + logf(s0);
#pragma unroll
  for (int c4 = 0; c4 < 10; ++c4) {
    float4 o = make_float4(acc[c4 * 4 + 0] - l0, acc[c4 * 4 + 1] - l0,
                           acc[c4 * 4 + 2] - l0, acc[c4 * 4 + 3] - l0);
    *(float4*)&out[(size_t)n0 * 40 + c4 * 4] = o;
  }
}

// ---------- launch ----------
extern "C" void kernel_launch(void* const* d_in, const int* in_sizes, int n_in,
                              void* d_out, int out_size, void* d_ws, size_t ws_size,
                              hipStream_t stream) {
  const float* x  = (const float*)d_in[0];
  const int*   ei = (const int*)d_in[1];
  const float* W1 = (const float*)d_in[2];
  const float* b1 = (const float*)d_in[3];
  const float* g1 = (const float*)d_in[4];
  const float* t1 = (const float*)d_in[5];
  const float* W2 = (const float*)d_in[6];
  const float* b2 = (const float*)d_in[7];
  const float* g2 = (const float*)d_in[8];
  const float* t2 = (const float*)d_in[9];
  const float* W3 = (const float*)d_in[10];
  const float* b3 = (const float*)d_in[11];
  const float* g3 = (const float*)d_in[12];
  const float* t3 = (const float*)d_in[13];
  const float* Wf = (const float*)d_in[14];
  const float* bf = (const float*)d_in[15];
  float* out = (float*)d_out;

  const int N = in_sizes[0] / 128;
  const int E = in_sizes[1] / 2;
  const int* src = ei;
  const int* dst = ei + E;
  const int NBUK = (N + 127) >> GRP_SHIFT;
  const int NEB  = (E + PCHUNK - 1) / PCHUNK;
  const int ZOFF = N * 128;  // byte offset of the zero row in hs

  char* p = (char*)d_ws;
  auto carve = [&](size_t bytes) -> char* {
    char* r = p;
    p += (bytes + 255) & ~(size_t)255;
    return r;
  };
  int*      bcnt    = (int*)carve((size_t)(NBUK + 1) * 4);  // +1 = gcur
  int*      gcur    = bcnt + NBUK;
  unsigned* pairs   = (unsigned*)carve((size_t)NBUK * BCAP * 4);
  int*      csr     = (int*)carve(((size_t)E + 15 * (size_t)N + 256) * 4);
  int2*     noff    = (int2*)carve((size_t)N * 8);
  float*    dinv    = (float*)carve((size_t)N * 4);
  unsigned short* hs = (unsigned short*)carve(((size_t)N * 64 + 64) * 2);  // +1 zero row
  float*    hA      = (float*)carve((size_t)N * 64 * 4);
  float*    hB      = (float*)carve((size_t)N * 64 * 4);
  (void)ws_size; (void)n_in; (void)out_size;

  dim3 B(256);
  dim3 B512(512);
  dim3 B1K(1024);
  (void)hipMemsetAsync(bcnt, 0, (size_t)(NBUK + 1) * 4, stream);   // bcnt + gcur
  k_partition<<<dim3(NEB), B1K, 0, stream>>>(src, dst, bcnt, pairs, E, NBUK);
  k_bucket_place<<<dim3(NBUK), B, 0, stream>>>(pairs, bcnt, gcur, noff, dinv, csr,
                                               (unsigned*)(hs + (size_t)N * 64), N, ZOFF);

  const int GB = (N + 63) / 64;
  const int GA = (N + 7) / 8;
  const int GF = (N + 255) / 256;
  const char* hsc = (const char*)hs;
  const uint4* c4p = (const uint4*)csr;
  // layer 1
  gemm_scale<128><<<dim3(GB), B, 0, stream>>>(x, W1, dinv, hs, N);
  k_agg<<<dim3(GA), B512, 0, stream>>>(hsc, c4p, noff, dinv, b1, g1, t1, hA, N);
  // layer 2
  gemm_scale<64><<<dim3(GB), B, 0, stream>>>(hA, W2, dinv, hs, N);
  k_agg<<<dim3(GA), B512, 0, stream>>>(hsc, c4p, noff, dinv, b2, g2, t2, hB, N);
  // layer 3
  gemm_scale<64><<<dim3(GB), B, 0, stream>>>(hB, W3, dinv, hs, N);
  k_agg<<<dim3(GA), B512, 0, stream>>>(hsc, c4p, noff, dinv, b3, g3, t3, hA, N);
  // final projection + log_softmax
  k_final<<<dim3(GF), B, 0, stream>>>(hA, Wf, bf, out, N);
}

// Round 16
// 267.209 us; speedup vs baseline: 1.0850x; 1.0182x over previous
//
#include <hip/hip_runtime.h>
#include <math.h>
#include <stdint.h>

#define LN_EPS 1e-5f
#define GRP_SHIFT 7           // 128 nodes per bucket
#define MAXBUK 1024           // N <= 131072
#define PCHUNK 8192           // edges per partition block (1024 threads x 8)
#define BCAP 4096             // fixed per-bucket capacity (mean 2048, huge margin)

// ---------- bf16 helpers (RNE) ----------
__device__ __forceinline__ unsigned short f2bf(float f) {
  unsigned int u = __float_as_uint(f);
  unsigned int r = u + 0x7fffu + ((u >> 16) & 1u);
  return (unsigned short)(r >> 16);
}
__device__ __forceinline__ float bfLo(unsigned v) { return __uint_as_float(v << 16); }
__device__ __forceinline__ float bfHi(unsigned v) { return __uint_as_float(v & 0xffff0000u); }

// ---------- CSR build: single-pass partition into fixed-capacity buckets ----------
// payload packed (src<<7)|dst_local (N < 2^25); per-(block,bucket) rank from LDS hist.
__global__ __launch_bounds__(1024) void k_partition(const int* __restrict__ src,
                                                    const int* __restrict__ dst,
                                                    int* __restrict__ bcnt,
                                                    unsigned* __restrict__ pairs, int E, int NB) {
  __shared__ int hist[MAXBUK];
  __shared__ int base[MAXBUK];
  int t = threadIdx.x;
  for (int i = t; i < NB; i += 1024) hist[i] = 0;
  __syncthreads();
  int e0 = blockIdx.x * PCHUNK;
  int e1 = min(e0 + PCHUNK, E);
  int sv[8], dv[8], rk[8];
#pragma unroll
  for (int j = 0; j < 8; ++j) {
    int i = e0 + t + j * 1024;
    if (i < e1) {
      sv[j] = src[i];
      dv[j] = dst[i];
      rk[j] = atomicAdd(&hist[dv[j] >> GRP_SHIFT], 1);
    } else {
      dv[j] = -1;
    }
  }
  __syncthreads();
  for (int i = t; i < NB; i += 1024) {
    int c = hist[i];
    base[i] = c ? (i * BCAP + atomicAdd(&bcnt[i], c)) : 0;
  }
  __syncthreads();
#pragma unroll
  for (int j = 0; j < 8; ++j) {
    if (dv[j] >= 0) {
      int b = dv[j] >> GRP_SHIFT;
      pairs[base[b] + rk[j]] = ((unsigned)sv[j] << GRP_SHIFT) | (unsigned)(dv[j] & 127);
    }
  }
}

// per-bucket: degrees (LDS), 16-aligned per-node slots funded by a global atomic
// cursor; csr holds BYTE offsets (src*128), pad slots hold ZOFF (zero row).
// block 0 also zeroes the hs zero-row (replaces a memset dispatch).
__global__ __launch_bounds__(256) void k_bucket_place(const unsigned* __restrict__ pairs,
                                                      const int* __restrict__ bcnt,
                                                      int* __restrict__ gcur,
                                                      int2* __restrict__ noff,
                                                      float* __restrict__ dinv,
                                                      int* __restrict__ csr,
                                                      unsigned* __restrict__ zrow,
                                                      int N, int ZOFF) {
  __shared__ int cnt[128];
  __shared__ int sc[128];
  __shared__ int sbase;
  int t = threadIdx.x;
  int b = blockIdx.x;
  int node0 = b << GRP_SHIFT;
  if (b == 0 && t < 32) zrow[t] = 0u;   // zero row of hs (128 B)
  if (t < 128) cnt[t] = 0;
  int beg = b * BCAP;
  int end = beg + bcnt[b];
  __syncthreads();
  for (int i = beg + t; i < end; i += 256) atomicAdd(&cnt[pairs[i] & 127u], 1);
  __syncthreads();
  int pcnt = 0;
  if (t < 128) { pcnt = (cnt[t] + 15) & ~15; sc[t] = pcnt; }
  __syncthreads();
  for (int o = 1; o < 128; o <<= 1) {
    int x = (t < 128 && t >= o) ? sc[t - o] : 0;
    __syncthreads();
    if (t < 128) sc[t] += x;
    __syncthreads();
  }
  if (t == 127) sbase = atomicAdd(gcur, sc[127]);
  __syncthreads();
  if (t < 128) {
    int off = sbase + sc[t] - pcnt;
    int node = node0 + t;
    if (node < N) {
      int d = cnt[t];
      noff[node] = make_int2(off, off + d);
      dinv[node] = d > 0 ? rsqrtf((float)d) : 0.f;
      for (int i = off + d; i < off + pcnt; ++i) csr[i] = ZOFF;  // zero-row pads
    }
    sc[t] = off;  // becomes write cursor
  }
  __syncthreads();
  for (int i = beg + t; i < end; i += 256) {
    unsigned pk = pairs[i];
    int pos = atomicAdd(&sc[pk & 127u], 1);
    csr[pos] = (int)(pk & ~127u);  // src*128 byte offset
  }
}

// ---------- GEMM: out[m] = bf16( dinv[m] * (A[m] @ W) ), A:[M][K] f32, W:[K][64] ----------
template <int K>
__global__ __launch_bounds__(256) void gemm_scale(const float* __restrict__ A,
                                                  const float* __restrict__ W,
                                                  const float* __restrict__ dinv,
                                                  unsigned short* __restrict__ out, int M) {
  __shared__ float xs[16][64];   // transposed A tile: xs[k][m]
  __shared__ float wsh[16][64];  // W tile: wsh[k][c]
  int t = threadIdx.x;
  int m0 = blockIdx.x * 64;
  int lm = t >> 2;
  int lk = (t & 3) << 2;
  int mr = (t & 15) << 2;
  int cc = (t >> 4) << 2;
  float acc[4][4] = {{0.f}};
  int gm = m0 + lm;
  const bool mok = gm < M;
  for (int kc = 0; kc < K; kc += 16) {
    float4 av = make_float4(0.f, 0.f, 0.f, 0.f);
    if (mok) av = *(const float4*)&A[(size_t)gm * K + kc + lk];
    float wv[4];
#pragma unroll
    for (int r = 0; r < 4; ++r) {
      int k = (t >> 6) + (r << 2);
      wv[r] = W[(size_t)(kc + k) * 64 + (t & 63)];
    }
    __syncthreads();
    xs[lk + 0][lm] = av.x;
    xs[lk + 1][lm] = av.y;
    xs[lk + 2][lm] = av.z;
    xs[lk + 3][lm] = av.w;
#pragma unroll
    for (int r = 0; r < 4; ++r) {
      int k = (t >> 6) + (r << 2);
      wsh[k][t & 63] = wv[r];
    }
    __syncthreads();
#pragma unroll
    for (int k = 0; k < 16; ++k) {
      float4 a4 = *(const float4*)&xs[k][mr];
      float4 b4 = *(const float4*)&wsh[k][cc];
      float a[4] = {a4.x, a4.y, a4.z, a4.w};
      float b[4] = {b4.x, b4.y, b4.z, b4.w};
#pragma unroll
      for (int i = 0; i < 4; ++i)
#pragma unroll
        for (int j = 0; j < 4; ++j) acc[i][j] = fmaf(a[i], b[j], acc[i][j]);
    }
  }
#pragma unroll
  for (int i = 0; i < 4; ++i) {
    int row = m0 + mr + i;
    if (row < M) {
      float sc = dinv[row];
      ushort4 o;
      o.x = f2bf(acc[i][0] * sc);
      o.y = f2bf(acc[i][1] * sc);
      o.z = f2bf(acc[i][2] * sc);
      o.w = f2bf(acc[i][3] * sc);
      *(ushort4*)&out[(size_t)row * 64 + cc] = o;
    }
  }
}

// ---------- aggregation + bias + LayerNorm + ReLU (proven floor structure) ----------
// 4 nodes per 256-thread block (best-measured shape: 46.7 us); wave per node;
// lane = (q = lane>>4, fl = lane&15); fl owns features 4fl..4fl+3.
// csr holds byte offsets in 16-aligned, zero-row-padded slots -> branch/mask/shuffle-free
// inner loop: 1 uint4 idx load + 4 gathers per 16 edges.
__global__ __launch_bounds__(256) void k_agg(const char* __restrict__ hsb,
                                             const uint4* __restrict__ csr4,
                                             const int2* __restrict__ noff,
                                             const float* __restrict__ dinv,
                                             const float* __restrict__ b,
                                             const float* __restrict__ g,
                                             const float* __restrict__ tt,
                                             float* __restrict__ out, int n) {
  int lane = threadIdx.x & 63;
  int q = lane >> 4;
  int fl = lane & 15;
  int node = blockIdx.x * 4 + (threadIdx.x >> 6);
  if (node >= n) return;
  int2 be = noff[node];
  int ng = (be.y - be.x + 15) >> 4;   // 16-edge groups (padded slot)
  float a0 = 0.f, a1 = 0.f, a2 = 0.f, a3 = 0.f;
  unsigned fo = (unsigned)fl * 8u;
  int c4 = (be.x >> 2) + q;
  for (; ng > 0; --ng, c4 += 4) {
    uint4 iv = csr4[c4];                 // this lane's 4 edges (byte offsets)
    uint2 w0 = *(const uint2*)(hsb + (iv.x + fo));
    uint2 w1 = *(const uint2*)(hsb + (iv.y + fo));
    uint2 w2 = *(const uint2*)(hsb + (iv.z + fo));
    uint2 w3 = *(const uint2*)(hsb + (iv.w + fo));
    a0 += bfLo(w0.x); a1 += bfHi(w0.x); a2 += bfLo(w0.y); a3 += bfHi(w0.y);
    a0 += bfLo(w1.x); a1 += bfHi(w1.x); a2 += bfLo(w1.y); a3 += bfHi(w1.y);
    a0 += bfLo(w2.x); a1 += bfHi(w2.x); a2 += bfLo(w2.y); a3 += bfHi(w2.y);
    a0 += bfLo(w3.x); a1 += bfHi(w3.x); a2 += bfLo(w3.y); a3 += bfHi(w3.y);
  }

  // combine the 4 quarters (independent 2-step chains)
  a0 += __shfl_xor(a0, 16, 64); a0 += __shfl_xor(a0, 32, 64);
  a1 += __shfl_xor(a1, 16, 64); a1 += __shfl_xor(a1, 32, 64);
  a2 += __shfl_xor(a2, 16, 64); a2 += __shfl_xor(a2, 32, 64);
  a3 += __shfl_xor(a3, 16, 64); a3 += __shfl_xor(a3, 32, 64);

  float dv = dinv[node];
  float4 bb = *(const float4*)&b[fl * 4];
  float v0 = fmaf(a0, dv, bb.x);
  float v1 = fmaf(a1, dv, bb.y);
  float v2 = fmaf(a2, dv, bb.z);
  float v3 = fmaf(a3, dv, bb.w);
  float s  = v0 + v1 + v2 + v3;
  float s2 = fmaf(v0, v0, fmaf(v1, v1, fmaf(v2, v2, v3 * v3)));
#pragma unroll
  for (int m = 1; m < 16; m <<= 1) {   // two independent 4-step chains
    s  += __shfl_xor(s, m, 64);
    s2 += __shfl_xor(s2, m, 64);
  }
  float mu = s * 0.015625f;            // /64
  float var = fmaxf(s2 * 0.015625f - mu * mu, 0.f);
  float rs = rsqrtf(var + LN_EPS);
  float4 gg = *(const float4*)&g[fl * 4];
  float4 t4 = *(const float4*)&tt[fl * 4];
  if (q == 0) {
    float4 o;
    o.x = fmaxf(fmaf(gg.x * (v0 - mu), rs, t4.x), 0.f);
    o.y = fmaxf(fmaf(gg.y * (v1 - mu), rs, t4.y), 0.f);
    o.z = fmaxf(fmaf(gg.z * (v2 - mu), rs, t4.z), 0.f);
    o.w = fmaxf(fmaf(gg.w * (v3 - mu), rs, t4.w), 0.f);
    *(float4*)&out[(size_t)node * 64 + fl * 4] = o;
  }
}

// ---------- final: logits = h @ Wf + bf ; log_softmax (1 node/thread) ----------
__global__ __launch_bounds__(256) void k_final(const float* __restrict__ h,
                                               const float* __restrict__ Wf,
                                               const float* __restrict__ bf,
                                               float* __restrict__ out, int n) {
  __shared__ float Wl[64 * 40];
  __shared__ float bl[40];
  int t = threadIdx.x;
  for (int i = t; i < 64 * 40; i += 256) Wl[i] = Wf[i];
  if (t < 40) bl[t] = bf[t];
  __syncthreads();
  int n0 = blockIdx.x * 256 + t;
  if (n0 >= n) return;
  float acc[40];
#pragma unroll
  for (int c = 0; c < 40; ++c) acc[c] = bl[c];
  const float* h0 = &h[(size_t)n0 * 64];
#pragma unroll 2
  for (int k4 = 0; k4 < 16; ++k4) {
    float4 a4 = *(const float4*)&h0[k4 * 4];
    float av[4] = {a4.x, a4.y, a4.z, a4.w};
#pragma unroll
    for (int j = 0; j < 4; ++j) {
      int k = k4 * 4 + j;
#pragma unroll
      for (int c4 = 0; c4 < 10; ++c4) {
        float4 w = *(const float4*)&Wl[k * 40 + c4 * 4];  // uniform -> broadcast
        acc[c4 * 4 + 0] = fmaf(av[j], w.x, acc[c4 * 4 + 0]);
        acc[c4 * 4 + 1] = fmaf(av[j], w.y, acc[c4 * 4 + 1]);
        acc[c4 * 4 + 2] = fmaf(av[j], w.z, acc[c4 * 4 + 2]);
        acc[c4 * 4 + 3] = fmaf(av[j], w.w, acc[c4 * 4 + 3]);
      }
    }
  }
  float m0 = acc[0];
#pragma unroll
  for (int c = 1; c < 40; ++c) m0 = fmaxf(m0, acc[c]);
  float s0 = 0.f;
#pragma unroll
  for (int c = 0; c < 40; ++c) s0 += expf(acc[c] - m0);
  float l0 = m0 + logf(s0);
#pragma unroll
  for (int c4 = 0; c4 < 10; ++c4) {
    float4 o = make_float4(acc[c4 * 4 + 0] - l0, acc[c4 * 4 + 1] - l0,
                           acc[c4 * 4 + 2] - l0, acc[c4 * 4 + 3] - l0);
    *(float4*)&out[(size_t)n0 * 40 + c4 * 4] = o;
  }
}

// ---------- launch ----------
extern "C" void kernel_launch(void* const* d_in, const int* in_sizes, int n_in,
                              void* d_out, int out_size, void* d_ws, size_t ws_size,
                              hipStream_t stream) {
  const float* x  = (const float*)d_in[0];
  const int*   ei = (const int*)d_in[1];
  const float* W1 = (const float*)d_in[2];
  const float* b1 = (const float*)d_in[3];
  const float* g1 = (const float*)d_in[4];
  const float* t1 = (const float*)d_in[5];
  const float* W2 = (const float*)d_in[6];
  const float* b2 = (const float*)d_in[7];
  const float* g2 = (const float*)d_in[8];
  const float* t2 = (const float*)d_in[9];
  const float* W3 = (const float*)d_in[10];
  const float* b3 = (const float*)d_in[11];
  const float* g3 = (const float*)d_in[12];
  const float* t3 = (const float*)d_in[13];
  const float* Wf = (const float*)d_in[14];
  const float* bf = (const float*)d_in[15];
  float* out = (float*)d_out;

  const int N = in_sizes[0] / 128;
  const int E = in_sizes[1] / 2;
  const int* src = ei;
  const int* dst = ei + E;
  const int NBUK = (N + 127) >> GRP_SHIFT;
  const int NEB  = (E + PCHUNK - 1) / PCHUNK;
  const int ZOFF = N * 128;  // byte offset of the zero row in hs

  char* p = (char*)d_ws;
  auto carve = [&](size_t bytes) -> char* {
    char* r = p;
    p += (bytes + 255) & ~(size_t)255;
    return r;
  };
  int*      bcnt    = (int*)carve((size_t)(NBUK + 1) * 4);  // +1 = gcur
  int*      gcur    = bcnt + NBUK;
  unsigned* pairs   = (unsigned*)carve((size_t)NBUK * BCAP * 4);
  int*      csr     = (int*)carve(((size_t)E + 15 * (size_t)N + 256) * 4);
  int2*     noff    = (int2*)carve((size_t)N * 8);
  float*    dinv    = (float*)carve((size_t)N * 4);
  unsigned short* hs = (unsigned short*)carve(((size_t)N * 64 + 64) * 2);  // +1 zero row
  float*    hA      = (float*)carve((size_t)N * 64 * 4);
  float*    hB      = (float*)carve((size_t)N * 64 * 4);
  (void)ws_size; (void)n_in; (void)out_size;

  dim3 B(256);
  dim3 B1K(1024);
  (void)hipMemsetAsync(bcnt, 0, (size_t)(NBUK + 1) * 4, stream);   // bcnt + gcur
  k_partition<<<dim3(NEB), B1K, 0, stream>>>(src, dst, bcnt, pairs, E, NBUK);
  k_bucket_place<<<dim3(NBUK), B, 0, stream>>>(pairs, bcnt, gcur, noff, dinv, csr,
                                               (unsigned*)(hs + (size_t)N * 64), N, ZOFF);

  const int GB = (N + 63) / 64;
  const int GA = (N + 3) / 4;
  const int GF = (N + 255) / 256;
  const char* hsc = (const char*)hs;
  const uint4* c4p = (const uint4*)csr;
  // layer 1
  gemm_scale<128><<<dim3(GB), B, 0, stream>>>(x, W1, dinv, hs, N);
  k_agg<<<dim3(GA), B, 0, stream>>>(hsc, c4p, noff, dinv, b1, g1, t1, hA, N);
  // layer 2
  gemm_scale<64><<<dim3(GB), B, 0, stream>>>(hA, W2, dinv, hs, N);
  k_agg<<<dim3(GA), B, 0, stream>>>(hsc, c4p, noff, dinv, b2, g2, t2, hB, N);
  // layer 3
  gemm_scale<64><<<dim3(GB), B, 0, stream>>>(hB, W3, dinv, hs, N);
  k_agg<<<dim3(GA), B, 0, stream>>>(hsc, c4p, noff, dinv, b3, g3, t3, hA, N);
  // final projection + log_softmax
  k_final<<<dim3(GF), B, 0, stream>>>(hA, Wf, bf, out, N);
}